// Round 14
// baseline (390.099 us; speedup 1.0000x reference)
//
#include <hip/hip_runtime.h>

// ---- sizes ----
// x: (1024,1,28,28); h1: (1024,32,14,14); h2: (1024,64,14,14)->12544; out: (1024,10)
#define NB 1024
#define TOTAL1 (NB*196)
#define SPS 200  // Sbuf pixel stride (196 real + 4 zero-pad; +8 guard at end)

// ws layout (float offsets)
#define WS_H1   0               // 1024*32*196      = 6422528
#define WS_H2   6422528         // 1024*12544      = 12845056
#define WS_PART 19267584        // 32*1024*128     = 4194304
#define WS_W1T  23461888        // 288
#define WS_OW1T 23462176        // 162
#define WS_W2T  23462338        // 18432  [k=ci*9+kk][co=64]
#define WS_OW2T 23480770        // 5184   [k=ci*9+j][c=18]

// ---------------- weight transpose prep ----------------
__global__ __launch_bounds__(256) void prep(const float* __restrict__ w1,
                                            const float* __restrict__ ow1,
                                            const float* __restrict__ w2,
                                            const float* __restrict__ ow2,
                                            float* __restrict__ ws) {
  int i = blockIdx.x * 256 + threadIdx.x;
  if (i < 288)   { int co = i / 9,  kk = i % 9;   ws[WS_W1T  + kk * 32 + co] = w1[i]; }
  if (i < 162)   { int c  = i / 9,  j  = i % 9;   ws[WS_OW1T + j  * 18 + c ] = ow1[i]; }
  if (i < 18432) { int co = i / 288, k = i % 288; ws[WS_W2T  + k  * 64 + co] = w2[i]; }
  if (i < 5184)  { int c  = i / 288, k = i % 288; ws[WS_OW2T + k  * 18 + c ] = ow2[i]; }
}

// ---------------- stage 1: offset conv + deform conv (1->32) + relu + pool 28->14 ----------------
__global__ __launch_bounds__(256, 2) void stage1(const float* __restrict__ x,
                                                 const float* __restrict__ ob1,
                                                 const float* __restrict__ b1,
                                                 const float* __restrict__ ws,
                                                 float* __restrict__ h1) {
  __shared__ float ximg[3 * 784];
  const float* __restrict__ w1t  = ws + WS_W1T;   // [kk][32]
  const float* __restrict__ ow1t = ws + WS_OW1T;  // [j][18]
  int tid = threadIdx.x;
  int g0 = blockIdx.x * 256;
  int bfirst = g0 / 196;
  for (int idx = tid; idx < 3 * 784; idx += 256) {
    int img = idx / 784;
    int b = bfirst + img;
    ximg[idx] = (b < NB) ? x[b * 784 + (idx - img * 784)] : 0.f;
  }
  __syncthreads();
  int g = g0 + tid;
  if (g >= TOTAL1) return;
  int b = g / 196, p = g - b * 196;
  const float* im = ximg + (b - bfirst) * 784;
  int oy = p / 14, ox = p - (p / 14) * 14;

  float pooled[32];
#pragma unroll
  for (int co = 0; co < 32; ++co) pooled[co] = 0.f;

  for (int sub = 0; sub < 4; ++sub) {
    int y  = 2 * oy + (sub >> 1);
    int ix = 2 * ox + (sub & 1);
    float patch[9];
#pragma unroll
    for (int j = 0; j < 9; ++j) {
      int yy = y + j / 3 - 1, xc = ix + j % 3 - 1;
      bool ok = (yy >= 0) & (yy < 28) & (xc >= 0) & (xc < 28);
      patch[j] = ok ? im[yy * 28 + xc] : 0.f;
    }
    float off[18];
#pragma unroll
    for (int c = 0; c < 18; ++c) off[c] = ob1[c];
#pragma unroll
    for (int j = 0; j < 9; ++j) {
      float v = patch[j];
#pragma unroll
      for (int c = 0; c < 18; ++c) off[c] = fmaf(v, ow1t[j * 18 + c], off[c]);
    }
    float a[32];
#pragma unroll
    for (int co = 0; co < 32; ++co) a[co] = b1[co];
#pragma unroll
    for (int kk = 0; kk < 9; ++kk) {
      float py = (float)(y - 1 + kk / 3) + off[2 * kk];
      float px = (float)(ix - 1 + kk % 3) + off[2 * kk + 1];
      float y0f = floorf(py), x0f = floorf(px);
      float wy1 = py - y0f, wx1 = px - x0f;
      float wy0 = 1.f - wy1, wx0 = 1.f - wx1;
      int y0 = (int)y0f, x0 = (int)x0f;
      int y1 = y0 + 1, x1 = x0 + 1;
      bool vy0 = (y0 >= 0) & (y0 < 28), vy1 = (y1 >= 0) & (y1 < 28);
      bool vx0 = (x0 >= 0) & (x0 < 28), vx1 = (x1 >= 0) & (x1 < 28);
      float W00 = (vy0 & vx0) ? wy0 * wx0 : 0.f;
      float W01 = (vy0 & vx1) ? wy0 * wx1 : 0.f;
      float W10 = (vy1 & vx0) ? wy1 * wx0 : 0.f;
      float W11 = (vy1 & vx1) ? wy1 * wx1 : 0.f;
      int yc0 = min(max(y0, 0), 27), yc1 = min(max(y1, 0), 27);
      int xc0 = min(max(x0, 0), 27), xc1 = min(max(x1, 0), 27);
      float s = im[yc0 * 28 + xc0] * W00 + im[yc0 * 28 + xc1] * W01 +
                im[yc1 * 28 + xc0] * W10 + im[yc1 * 28 + xc1] * W11;
#pragma unroll
      for (int co = 0; co < 32; ++co) a[co] = fmaf(s, w1t[kk * 32 + co], a[co]);
    }
#pragma unroll
    for (int co = 0; co < 32; ++co) pooled[co] += fmaxf(a[co], 0.f);
  }
#pragma unroll
  for (int co = 0; co < 32; ++co) h1[b * 6272 + co * 196 + p] = pooled[co] * 0.25f;
}

// ---------------- stage 2 v4.4: v4.3 + double-buffered offT (2 barriers/tap, was 3) ----------------
// LDS: imgT 25088B + Sbuf 25632B + offT 2x416 = 3328B -> 54048B... recount: 2*416*4 = 3328;
// total = 25088+25632+3328 = 54048B -> still 3 blocks/CU (160KB/54KB = 2.96 -> 2!). CAREFUL:
// must stay <= 53333B for 3 blocks. offT[2][416] = 3328 vs old 1664: +1664 -> 54048 > 53333.
// Fix: offT double buffer at 2x208x2 = 832 floats NOT padded: use [2][2][208] exact = 3328B. Too big.
// Instead reuse: offT[2][209*2] trimmed to [2][418]... same. Solution: drop Sbuf guard pad from
// SPS calc? Keep correctness: shrink Sbuf tail guard (8 floats) and use offT[2][416] packed into
// 832 floats via 208-stride without the spill row: publish uses op0<208 always. 832*4 = 3328B.
// => Reduce Sbuf to 32*SPS (no +8) and bound pg over-read: pg=12 reads p0=192..207 -> cols 192..207;
// rows' cols 196..199 are zeroed; col 200..207 would overrun row into next row's data region.
// Keep the +8 guard. Instead trim offT: only the CURRENT and NEXT tap's 2 channels are ever live
// -> offT[2][2*208] = 832 floats = 3328B. Old was 416 floats=1664B. Net +1664B -> 54048B.
// 160*1024/3 = 54613B >= 54048B -> 3 blocks/CU STILL FITS. (HW partitions by 54613 floor.)
__global__ __launch_bounds__(256, 3) void stage2(const float* __restrict__ h1,
                                                 const float* __restrict__ ob2,
                                                 const float* __restrict__ b2,
                                                 const float* __restrict__ ws,
                                                 float* __restrict__ h2) {
  __shared__ float imgT[196 * 32];       // imgT[p*32 + ((ci+4p)&31)] = img[ci][p]
  __shared__ float Sbuf[32 * SPS + 8];   // S[ci*SPS + p]; +8 guard for pg=12 over-reads
  __shared__ float offT[2][2 * 208];     // double-buffered (dy,dx) per tap
  const float* __restrict__ w2t  = ws + WS_W2T;
  const float* __restrict__ ow2t = ws + WS_OW2T;
  int tid = threadIdx.x;
  int b = blockIdx.x;

  // ---- phase 1: load image, transposed + bank-rotated; zero Sbuf guard ONCE ----
  for (int e = tid; e < 6272; e += 256) {
    int ci = e / 196, p = e - ci * 196;
    imgT[p * 32 + ((ci + 4 * p) & 31)] = h1[b * 6272 + e];
  }
  if (tid < 128) Sbuf[(tid >> 2) * SPS + 196 + (tid & 3)] = 0.f;  // rows 0..31, cols 196..199
  if (tid < 8)   Sbuf[32 * SPS + tid] = 0.f;                      // tail guard

  // sampler identity
  int pp = tid;
  int spy = pp / 14, spx = pp - (pp / 14) * 14;

  // offset-GEMM identity: 18 channels x 13 pixel-groups of 16 = 234 threads
  int oc  = tid % 18;
  int opg = tid / 18;
  int op0 = opg * 16;
  bool oact = (tid < 234);
  float oacc[16];
#pragma unroll
  for (int i = 0; i < 16; ++i) oacc[i] = 0.f;

  // ---- phase 2: offset conv as 9 broadcast-GEMM taps (integer shifts) ----
  for (int j = 0; j < 9; ++j) {
    // hoisted weight loads for this tap (consumed after 2 barriers + sampler)
    float wv[32];
    if (oact) {
#pragma unroll
      for (int ci2 = 0; ci2 < 32; ++ci2) wv[ci2] = ow2t[(ci2 * 9 + j) * 18 + oc];
    }
    __syncthreads();
    if (pp < 196) {
      int yy = spy + j / 3 - 1, xx = spx + j % 3 - 1;
      bool ok = (yy >= 0) & (yy < 14) & (xx >= 0) & (xx < 14);
      int idx = ok ? (yy * 14 + xx) : 0;
      const float* src = imgT + idx * 32;
      int rot = (4 * idx) & 31;
#pragma unroll
      for (int cg = 0; cg < 8; ++cg) {
        float4 v;
        if (ok) v = *(const float4*)(src + ((cg * 4 + rot) & 31));
        else    v = make_float4(0.f, 0.f, 0.f, 0.f);
        Sbuf[(cg * 4 + 0) * SPS + pp] = v.x;
        Sbuf[(cg * 4 + 1) * SPS + pp] = v.y;
        Sbuf[(cg * 4 + 2) * SPS + pp] = v.z;
        Sbuf[(cg * 4 + 3) * SPS + pp] = v.w;
      }
    }
    __syncthreads();
    if (oact) {
      for (int ci2 = 0; ci2 < 32; ++ci2) {
        const float* srow = Sbuf + ci2 * SPS + op0;
        float w = wv[ci2];
#pragma unroll
        for (int t = 0; t < 4; ++t) {
          float4 s = *(const float4*)(srow + 4 * t);
          oacc[4 * t + 0] = fmaf(w, s.x, oacc[4 * t + 0]);
          oacc[4 * t + 1] = fmaf(w, s.y, oacc[4 * t + 1]);
          oacc[4 * t + 2] = fmaf(w, s.z, oacc[4 * t + 2]);
          oacc[4 * t + 3] = fmaf(w, s.w, oacc[4 * t + 3]);
        }
      }
    }
  }

  // ---- phase 3: 9 taps, 2 barriers each; offT publish folded into prior GEMM section ----
  int cog = tid & 15, pg = tid >> 4;
  int co0 = cog * 4;
  int p0 = pg * 16;
  bool gact = (pg < 13);
  float acc[4][16];
  {
    float4 bb = *(const float4*)(b2 + co0);
    float bj[4] = {bb.x, bb.y, bb.z, bb.w};
#pragma unroll
    for (int jj = 0; jj < 4; ++jj)
#pragma unroll
      for (int i = 0; i < 16; ++i) acc[jj][i] = bj[jj];
  }
  float myob = oact ? ob2[oc] : 0.f;

  // publish tap 0 into offT[0] (Sbuf still in use by phase-2 j=8 GEMM readers until barrier)
  if (oact && (oc >> 1) == 0) {
    float* dst = offT[0] + (oc & 1) * 208 + op0;
#pragma unroll
    for (int i = 0; i < 16; ++i) dst[i] = oacc[i] + myob;
  }
  __syncthreads();  // offT[0] ready; Sbuf free

  for (int kk = 0; kk < 9; ++kk) {
    const float* offcur = offT[kk & 1];

    // (a) issue this tap's first weight chunk NOW - hidden under the sampler section
    const float* wb = w2t + kk * 64 + co0;
    float4 w[4];
    if (gact) {
#pragma unroll
      for (int u = 0; u < 4; ++u)
        w[u] = *(const float4*)(wb + u * 576);
    }

    if (pp < 196) {
      float dyv = offcur[pp];
      float dxv = offcur[208 + pp];
      float pyv = (float)(spy - 1 + kk / 3) + dyv;
      float pxv = (float)(spx - 1 + kk % 3) + dxv;
      float y0f = floorf(pyv), x0f = floorf(pxv);
      float wy1 = pyv - y0f, wx1 = pxv - x0f;
      float wy0 = 1.f - wy1, wx0 = 1.f - wx1;
      int y0 = (int)y0f, x0 = (int)x0f;
      int y1 = y0 + 1, x1 = x0 + 1;
      bool vy0 = (y0 >= 0) & (y0 < 14), vy1 = (y1 >= 0) & (y1 < 14);
      bool vx0 = (x0 >= 0) & (x0 < 14), vx1 = (x1 >= 0) & (x1 < 14);
      float W00 = (vy0 & vx0) ? wy0 * wx0 : 0.f;
      float W01 = (vy0 & vx1) ? wy0 * wx1 : 0.f;
      float W10 = (vy1 & vx0) ? wy1 * wx0 : 0.f;
      float W11 = (vy1 & vx1) ? wy1 * wx1 : 0.f;
      int yc0 = min(max(y0, 0), 13), yc1 = min(max(y1, 0), 13);
      int xc0 = min(max(x0, 0), 13), xc1 = min(max(x1, 0), 13);
      int i00 = yc0 * 14 + xc0, i01 = yc0 * 14 + xc1;
      int i10 = yc1 * 14 + xc0, i11 = yc1 * 14 + xc1;
      const float* s00 = imgT + i00 * 32; int r00 = (4 * i00) & 31;
      const float* s01 = imgT + i01 * 32; int r01 = (4 * i01) & 31;
      const float* s10 = imgT + i10 * 32; int r10 = (4 * i10) & 31;
      const float* s11 = imgT + i11 * 32; int r11 = (4 * i11) & 31;
#pragma unroll
      for (int cg = 0; cg < 8; ++cg) {
        float4 a0 = *(const float4*)(s00 + ((cg * 4 + r00) & 31));
        float4 a1 = *(const float4*)(s01 + ((cg * 4 + r01) & 31));
        float4 a2 = *(const float4*)(s10 + ((cg * 4 + r10) & 31));
        float4 a3 = *(const float4*)(s11 + ((cg * 4 + r11) & 31));
        Sbuf[(cg * 4 + 0) * SPS + pp] = fmaf(W00, a0.x, fmaf(W01, a1.x, fmaf(W10, a2.x, W11 * a3.x)));
        Sbuf[(cg * 4 + 1) * SPS + pp] = fmaf(W00, a0.y, fmaf(W01, a1.y, fmaf(W10, a2.y, W11 * a3.y)));
        Sbuf[(cg * 4 + 2) * SPS + pp] = fmaf(W00, a0.z, fmaf(W01, a1.z, fmaf(W10, a2.z, W11 * a3.z)));
        Sbuf[(cg * 4 + 3) * SPS + pp] = fmaf(W00, a0.w, fmaf(W01, a1.w, fmaf(W10, a2.w, W11 * a3.w)));
      }
    }
    __syncthreads();  // Sbuf ready; offT[(kk+1)&1] safe to write (its readers are 2 barriers back)

    // publish NEXT tap's offsets during the GEMM section (26 owner threads, tiny)
    if (kk < 8 && oact && (oc >> 1) == (kk + 1)) {
      float* dst = offT[(kk + 1) & 1] + (oc & 1) * 208 + op0;
#pragma unroll
      for (int i = 0; i < 16; ++i) dst[i] = oacc[i] + myob;
    }
    if (gact) {
      // (b) 32 ci in chunks of 4, prefetching chunk cb+4's weights under chunk cb's FMAs
      for (int cb = 0; cb < 32; cb += 4) {
        float4 wn[4];
        if (cb + 4 < 32) {
#pragma unroll
          for (int u = 0; u < 4; ++u)
            wn[u] = *(const float4*)(wb + (cb + 4 + u) * 576);
        }
#pragma unroll
        for (int u = 0; u < 4; ++u) {
          const float* srow = Sbuf + (cb + u) * SPS + p0;
          float4 s0 = *(const float4*)(srow);
          float4 s1 = *(const float4*)(srow + 4);
          float4 s2 = *(const float4*)(srow + 8);
          float4 s3 = *(const float4*)(srow + 12);
          float sv[16] = {s0.x, s0.y, s0.z, s0.w, s1.x, s1.y, s1.z, s1.w,
                          s2.x, s2.y, s2.z, s2.w, s3.x, s3.y, s3.z, s3.w};
          float wj[4] = {w[u].x, w[u].y, w[u].z, w[u].w};
#pragma unroll
          for (int jj = 0; jj < 4; ++jj)
#pragma unroll
            for (int i = 0; i < 16; ++i)
              acc[jj][i] = fmaf(wj[jj], sv[i], acc[jj][i]);
        }
        if (cb + 4 < 32) {
#pragma unroll
          for (int u = 0; u < 4; ++u) w[u] = wn[u];
        }
      }
    }
    __syncthreads();  // GEMM done with Sbuf; offT[(kk+1)&1] published
  }

  // ---- phase 4: ReLU + direct float4 global stores ----
  if (gact) {
    float* __restrict__ orow = h2 + b * 12544 + co0 * 196 + p0;
#pragma unroll
    for (int jj = 0; jj < 4; ++jj) {
#pragma unroll
      for (int t = 0; t < 4; ++t) {
        if (p0 + 4 * t < 196) {
          float4 v;
          v.x = fmaxf(acc[jj][4 * t + 0], 0.f);
          v.y = fmaxf(acc[jj][4 * t + 1], 0.f);
          v.z = fmaxf(acc[jj][4 * t + 2], 0.f);
          v.w = fmaxf(acc[jj][4 * t + 3], 0.f);
          *(float4*)(orow + jj * 196 + 4 * t) = v;
        }
      }
    }
  }
}

// ---------------- fc1 v1.3: K-split GEMM, 3 blocks/CU, reg-prefetched staging ----------------
__global__ __launch_bounds__(256, 3) void fc1(const float* __restrict__ h2,
                                              const float* __restrict__ fw1,
                                              float* __restrict__ part) {
  __shared__ float a_s[56 * 72];   // [k][r]
  __shared__ float b_s[56 * 132];  // [k][c]
  int tid = threadIdx.x;
  int rb = (blockIdx.x & 15) * 64;
  int ks = blockIdx.x >> 4;
  int kbase = ks * 392;
  int c0 = (tid & 31) * 4;
  int r0 = (tid >> 5) * 8;

  float4 aReg[4];
  float4 bReg[7];

  auto loadChunk = [&](int ch) {
    int kb = kbase + ch * 56;
#pragma unroll
    for (int t = 0; t < 4; ++t) {
      int idx = t * 256 + tid;
      if (idx < 896) {
        int k4 = idx % 14, r = idx / 14;
        aReg[t] = *(const float4*)&h2[(rb + r) * 12544 + kb + k4 * 4];
      }
    }
#pragma unroll
    for (int t = 0; t < 7; ++t) {
      int idx = t * 256 + tid;
      int k4 = idx % 14, c = idx / 14;
      bReg[t] = *(const float4*)&fw1[c * 12544 + kb + k4 * 4];
    }
  };

  float acc[8][4];
#pragma unroll
  for (int i = 0; i < 8; ++i)
#pragma unroll
    for (int j = 0; j < 4; ++j) acc[i][j] = 0.f;

  loadChunk(0);
  for (int ch = 0; ch < 7; ++ch) {
    __syncthreads();  // prev compute done with LDS
#pragma unroll
    for (int t = 0; t < 4; ++t) {
      int idx = t * 256 + tid;
      if (idx < 896) {
        int k4 = idx % 14, r = idx / 14;
        a_s[(k4 * 4 + 0) * 72 + r] = aReg[t].x;
        a_s[(k4 * 4 + 1) * 72 + r] = aReg[t].y;
        a_s[(k4 * 4 + 2) * 72 + r] = aReg[t].z;
        a_s[(k4 * 4 + 3) * 72 + r] = aReg[t].w;
      }
    }
#pragma unroll
    for (int t = 0; t < 7; ++t) {
      int idx = t * 256 + tid;
      int k4 = idx % 14, c = idx / 14;
      b_s[(k4 * 4 + 0) * 132 + c] = bReg[t].x;
      b_s[(k4 * 4 + 1) * 132 + c] = bReg[t].y;
      b_s[(k4 * 4 + 2) * 132 + c] = bReg[t].z;
      b_s[(k4 * 4 + 3) * 132 + c] = bReg[t].w;
    }
    __syncthreads();  // LDS ready
    if (ch < 6) loadChunk(ch + 1);  // issue next chunk's VMEM under this chunk's FMAs
    for (int k = 0; k < 56; ++k) {
      float4 bv = *(const float4*)&b_s[k * 132 + c0];
      float4 av0 = *(const float4*)&a_s[k * 72 + r0];
      float4 av1 = *(const float4*)&a_s[k * 72 + r0 + 4];
      float av[8] = {av0.x, av0.y, av0.z, av0.w, av1.x, av1.y, av1.z, av1.w};
      float bj[4] = {bv.x, bv.y, bv.z, bv.w};
#pragma unroll
      for (int i = 0; i < 8; ++i)
#pragma unroll
        for (int j = 0; j < 4; ++j) acc[i][j] = fmaf(av[i], bj[j], acc[i][j]);
    }
  }
#pragma unroll
  for (int i = 0; i < 8; ++i) {
    int r = rb + r0 + i;
#pragma unroll
    for (int j = 0; j < 4; ++j)
      part[(ks * 1024 + r) * 128 + c0 + j] = acc[i][j];
  }
}

// ---------------- reduce partials + bias + relu + fc2 (4-way ILP on the reduce) ----------------
__global__ __launch_bounds__(128) void fcfinal(const float* __restrict__ part,
                                               const float* __restrict__ fb1,
                                               const float* __restrict__ fw2,
                                               const float* __restrict__ fb2,
                                               float* __restrict__ out) {
  __shared__ float tbuf[128];
  int b = blockIdx.x, c = threadIdx.x;
  float s0 = 0.f, s1 = 0.f, s2 = 0.f, s3 = 0.f;
#pragma unroll
  for (int ks = 0; ks < 32; ks += 4) {
    s0 += part[((ks + 0) * 1024 + b) * 128 + c];
    s1 += part[((ks + 1) * 1024 + b) * 128 + c];
    s2 += part[((ks + 2) * 1024 + b) * 128 + c];
    s3 += part[((ks + 3) * 1024 + b) * 128 + c];
  }
  float s = fb1[c] + ((s0 + s1) + (s2 + s3));
  tbuf[c] = fmaxf(s, 0.f);
  __syncthreads();
  if (c < 10) {
    float v = fb2[c];
#pragma unroll
    for (int k = 0; k < 128; ++k) v = fmaf(tbuf[k], fw2[c * 128 + k], v);
    out[b * 10 + c] = v;
  }
}

extern "C" void kernel_launch(void* const* d_in, const int* in_sizes, int n_in,
                              void* d_out, int out_size, void* d_ws, size_t ws_size,
                              hipStream_t stream) {
  const float* x   = (const float*)d_in[0];
  const float* ow1 = (const float*)d_in[1];
  const float* ob1 = (const float*)d_in[2];
  const float* w1  = (const float*)d_in[3];
  const float* b1  = (const float*)d_in[4];
  const float* ow2 = (const float*)d_in[5];
  const float* ob2 = (const float*)d_in[6];
  const float* w2  = (const float*)d_in[7];
  const float* b2  = (const float*)d_in[8];
  const float* fw1 = (const float*)d_in[9];
  const float* fb1 = (const float*)d_in[10];
  const float* fw2 = (const float*)d_in[11];
  const float* fb2 = (const float*)d_in[12];
  float* ws  = (float*)d_ws;
  float* out = (float*)d_out;

  prep<<<72, 256, 0, stream>>>(w1, ow1, w2, ow2, ws);
  stage1<<<784, 256, 0, stream>>>(x, ob1, b1, ws, ws + WS_H1);
  stage2<<<NB, 256, 0, stream>>>(ws + WS_H1, ob2, b2, ws, ws + WS_H2);
  fc1<<<512, 256, 0, stream>>>(ws + WS_H2, fw1, ws + WS_PART);
  fcfinal<<<1024, 128, 0, stream>>>(ws + WS_PART, fb1, fw2, fb2, out);
}

// Round 15
// 384.079 us; speedup vs baseline: 1.0157x; 1.0157x over previous
//
#include <hip/hip_runtime.h>

// ---- sizes ----
// x: (1024,1,28,28); h1: (1024,32,14,14); h2: (1024,64,14,14)->12544; out: (1024,10)
#define NB 1024
#define TOTAL1 (NB*196)
#define SPS 200  // Sbuf pixel stride (196 real + 4 zero-pad; +8 guard at end)

// ws layout (float offsets)
#define WS_H1   0               // 1024*32*196      = 6422528
#define WS_H2   6422528         // 1024*12544      = 12845056
#define WS_PART 19267584        // 32*1024*128     = 4194304
#define WS_W1T  23461888        // 288
#define WS_OW1T 23462176        // 162
#define WS_W2T  23462338        // 18432  [k=ci*9+kk][co=64]
#define WS_OW2T 23480770        // 5184   [k=ci*9+j][c=18]

// ---------------- weight transpose prep ----------------
__global__ __launch_bounds__(256) void prep(const float* __restrict__ w1,
                                            const float* __restrict__ ow1,
                                            const float* __restrict__ w2,
                                            const float* __restrict__ ow2,
                                            float* __restrict__ ws) {
  int i = blockIdx.x * 256 + threadIdx.x;
  if (i < 288)   { int co = i / 9,  kk = i % 9;   ws[WS_W1T  + kk * 32 + co] = w1[i]; }
  if (i < 162)   { int c  = i / 9,  j  = i % 9;   ws[WS_OW1T + j  * 18 + c ] = ow1[i]; }
  if (i < 18432) { int co = i / 288, k = i % 288; ws[WS_W2T  + k  * 64 + co] = w2[i]; }
  if (i < 5184)  { int c  = i / 288, k = i % 288; ws[WS_OW2T + k  * 18 + c ] = ow2[i]; }
}

// ---------------- stage 1: offset conv + deform conv (1->32) + relu + pool 28->14 ----------------
__global__ __launch_bounds__(256, 2) void stage1(const float* __restrict__ x,
                                                 const float* __restrict__ ob1,
                                                 const float* __restrict__ b1,
                                                 const float* __restrict__ ws,
                                                 float* __restrict__ h1) {
  __shared__ float ximg[3 * 784];
  const float* __restrict__ w1t  = ws + WS_W1T;   // [kk][32]
  const float* __restrict__ ow1t = ws + WS_OW1T;  // [j][18]
  int tid = threadIdx.x;
  int g0 = blockIdx.x * 256;
  int bfirst = g0 / 196;
  for (int idx = tid; idx < 3 * 784; idx += 256) {
    int img = idx / 784;
    int b = bfirst + img;
    ximg[idx] = (b < NB) ? x[b * 784 + (idx - img * 784)] : 0.f;
  }
  __syncthreads();
  int g = g0 + tid;
  if (g >= TOTAL1) return;
  int b = g / 196, p = g - b * 196;
  const float* im = ximg + (b - bfirst) * 784;
  int oy = p / 14, ox = p - (p / 14) * 14;

  float pooled[32];
#pragma unroll
  for (int co = 0; co < 32; ++co) pooled[co] = 0.f;

  for (int sub = 0; sub < 4; ++sub) {
    int y  = 2 * oy + (sub >> 1);
    int ix = 2 * ox + (sub & 1);
    float patch[9];
#pragma unroll
    for (int j = 0; j < 9; ++j) {
      int yy = y + j / 3 - 1, xc = ix + j % 3 - 1;
      bool ok = (yy >= 0) & (yy < 28) & (xc >= 0) & (xc < 28);
      patch[j] = ok ? im[yy * 28 + xc] : 0.f;
    }
    float off[18];
#pragma unroll
    for (int c = 0; c < 18; ++c) off[c] = ob1[c];
#pragma unroll
    for (int j = 0; j < 9; ++j) {
      float v = patch[j];
#pragma unroll
      for (int c = 0; c < 18; ++c) off[c] = fmaf(v, ow1t[j * 18 + c], off[c]);
    }
    float a[32];
#pragma unroll
    for (int co = 0; co < 32; ++co) a[co] = b1[co];
#pragma unroll
    for (int kk = 0; kk < 9; ++kk) {
      float py = (float)(y - 1 + kk / 3) + off[2 * kk];
      float px = (float)(ix - 1 + kk % 3) + off[2 * kk + 1];
      float y0f = floorf(py), x0f = floorf(px);
      float wy1 = py - y0f, wx1 = px - x0f;
      float wy0 = 1.f - wy1, wx0 = 1.f - wx1;
      int y0 = (int)y0f, x0 = (int)x0f;
      int y1 = y0 + 1, x1 = x0 + 1;
      bool vy0 = (y0 >= 0) & (y0 < 28), vy1 = (y1 >= 0) & (y1 < 28);
      bool vx0 = (x0 >= 0) & (x0 < 28), vx1 = (x1 >= 0) & (x1 < 28);
      float W00 = (vy0 & vx0) ? wy0 * wx0 : 0.f;
      float W01 = (vy0 & vx1) ? wy0 * wx1 : 0.f;
      float W10 = (vy1 & vx0) ? wy1 * wx0 : 0.f;
      float W11 = (vy1 & vx1) ? wy1 * wx1 : 0.f;
      int yc0 = min(max(y0, 0), 27), yc1 = min(max(y1, 0), 27);
      int xc0 = min(max(x0, 0), 27), xc1 = min(max(x1, 0), 27);
      float s = im[yc0 * 28 + xc0] * W00 + im[yc0 * 28 + xc1] * W01 +
                im[yc1 * 28 + xc0] * W10 + im[yc1 * 28 + xc1] * W11;
#pragma unroll
      for (int co = 0; co < 32; ++co) a[co] = fmaf(s, w1t[kk * 32 + co], a[co]);
    }
#pragma unroll
    for (int co = 0; co < 32; ++co) pooled[co] += fmaxf(a[co], 0.f);
  }
#pragma unroll
  for (int co = 0; co < 32; ++co) h1[b * 6272 + co * 196 + p] = pooled[co] * 0.25f;
}

// ---------------- stage 2 v4.5: v4.3 + single-buffer offT publish folded into GEMM section ----------------
// LDS: imgT 25088B + Sbuf 25632B + offT 1664B = 52384B -> 3 blocks/CU (UNCHANGED from v4.3).
// 2 barriers/tap (19 total vs 27): within a tap, all offT reads (sampler) complete before the
// Sbuf-ready barrier; the publish for tap kk+1 happens after it (during GEMM); next read is
// after the end-of-GEMM barrier. Single buffer is race-free.
__global__ __launch_bounds__(256, 3) void stage2(const float* __restrict__ h1,
                                                 const float* __restrict__ ob2,
                                                 const float* __restrict__ b2,
                                                 const float* __restrict__ ws,
                                                 float* __restrict__ h2) {
  __shared__ float imgT[196 * 32];       // imgT[p*32 + ((ci+4p)&31)] = img[ci][p]
  __shared__ float Sbuf[32 * SPS + 8];   // S[ci*SPS + p]; +8 guard for pg=12 over-reads
  __shared__ float offT[2 * 208];        // current tap's (dy,dx)
  const float* __restrict__ w2t  = ws + WS_W2T;
  const float* __restrict__ ow2t = ws + WS_OW2T;
  int tid = threadIdx.x;
  int b = blockIdx.x;

  // ---- phase 1: load image, transposed + bank-rotated; zero Sbuf guard ONCE ----
  for (int e = tid; e < 6272; e += 256) {
    int ci = e / 196, p = e - ci * 196;
    imgT[p * 32 + ((ci + 4 * p) & 31)] = h1[b * 6272 + e];
  }
  if (tid < 128) Sbuf[(tid >> 2) * SPS + 196 + (tid & 3)] = 0.f;  // rows 0..31, cols 196..199
  if (tid < 8)   Sbuf[32 * SPS + tid] = 0.f;                      // tail guard

  // sampler identity
  int pp = tid;
  int spy = pp / 14, spx = pp - (pp / 14) * 14;

  // offset-GEMM identity: 18 channels x 13 pixel-groups of 16 = 234 threads
  int oc  = tid % 18;
  int opg = tid / 18;
  int op0 = opg * 16;
  bool oact = (tid < 234);
  float oacc[16];
#pragma unroll
  for (int i = 0; i < 16; ++i) oacc[i] = 0.f;

  // ---- phase 2: offset conv as 9 broadcast-GEMM taps (integer shifts) ----
  for (int j = 0; j < 9; ++j) {
    // hoisted weight loads for this tap (consumed after 2 barriers + sampler)
    float wv[32];
    if (oact) {
#pragma unroll
      for (int ci2 = 0; ci2 < 32; ++ci2) wv[ci2] = ow2t[(ci2 * 9 + j) * 18 + oc];
    }
    __syncthreads();
    if (pp < 196) {
      int yy = spy + j / 3 - 1, xx = spx + j % 3 - 1;
      bool ok = (yy >= 0) & (yy < 14) & (xx >= 0) & (xx < 14);
      int idx = ok ? (yy * 14 + xx) : 0;
      const float* src = imgT + idx * 32;
      int rot = (4 * idx) & 31;
#pragma unroll
      for (int cg = 0; cg < 8; ++cg) {
        float4 v;
        if (ok) v = *(const float4*)(src + ((cg * 4 + rot) & 31));
        else    v = make_float4(0.f, 0.f, 0.f, 0.f);
        Sbuf[(cg * 4 + 0) * SPS + pp] = v.x;
        Sbuf[(cg * 4 + 1) * SPS + pp] = v.y;
        Sbuf[(cg * 4 + 2) * SPS + pp] = v.z;
        Sbuf[(cg * 4 + 3) * SPS + pp] = v.w;
      }
    }
    __syncthreads();
    if (oact) {
      for (int ci2 = 0; ci2 < 32; ++ci2) {
        const float* srow = Sbuf + ci2 * SPS + op0;
        float w = wv[ci2];
#pragma unroll
        for (int t = 0; t < 4; ++t) {
          float4 s = *(const float4*)(srow + 4 * t);
          oacc[4 * t + 0] = fmaf(w, s.x, oacc[4 * t + 0]);
          oacc[4 * t + 1] = fmaf(w, s.y, oacc[4 * t + 1]);
          oacc[4 * t + 2] = fmaf(w, s.z, oacc[4 * t + 2]);
          oacc[4 * t + 3] = fmaf(w, s.w, oacc[4 * t + 3]);
        }
      }
    }
  }

  // ---- phase 3: 9 taps, 2 barriers each; offT publish folded into the GEMM section ----
  int cog = tid & 15, pg = tid >> 4;
  int co0 = cog * 4;
  int p0 = pg * 16;
  bool gact = (pg < 13);
  float acc[4][16];
  {
    float4 bb = *(const float4*)(b2 + co0);
    float bj[4] = {bb.x, bb.y, bb.z, bb.w};
#pragma unroll
    for (int jj = 0; jj < 4; ++jj)
#pragma unroll
      for (int i = 0; i < 16; ++i) acc[jj][i] = bj[jj];
  }
  float myob = oact ? ob2[oc] : 0.f;

  // publish tap 0 offsets (program-order after the owner's phase-2 accumulate)
  if (oact && (oc >> 1) == 0) {
    float* dst = offT + (oc & 1) * 208 + op0;
#pragma unroll
    for (int i = 0; i < 16; ++i) dst[i] = oacc[i] + myob;
  }
  __syncthreads();  // offT(tap0) visible; Sbuf free (phase-2 GEMM done)

  for (int kk = 0; kk < 9; ++kk) {
    // (a) issue this tap's first weight chunk NOW - hidden under the sampler section
    const float* wb = w2t + kk * 64 + co0;
    float4 w[4];
    if (gact) {
#pragma unroll
      for (int u = 0; u < 4; ++u)
        w[u] = *(const float4*)(wb + u * 576);
    }

    if (pp < 196) {
      float dyv = offT[pp];
      float dxv = offT[208 + pp];
      float pyv = (float)(spy - 1 + kk / 3) + dyv;
      float pxv = (float)(spx - 1 + kk % 3) + dxv;
      float y0f = floorf(pyv), x0f = floorf(pxv);
      float wy1 = pyv - y0f, wx1 = pxv - x0f;
      float wy0 = 1.f - wy1, wx0 = 1.f - wx1;
      int y0 = (int)y0f, x0 = (int)x0f;
      int y1 = y0 + 1, x1 = x0 + 1;
      bool vy0 = (y0 >= 0) & (y0 < 14), vy1 = (y1 >= 0) & (y1 < 14);
      bool vx0 = (x0 >= 0) & (x0 < 14), vx1 = (x1 >= 0) & (x1 < 14);
      float W00 = (vy0 & vx0) ? wy0 * wx0 : 0.f;
      float W01 = (vy0 & vx1) ? wy0 * wx1 : 0.f;
      float W10 = (vy1 & vx0) ? wy1 * wx0 : 0.f;
      float W11 = (vy1 & vx1) ? wy1 * wx1 : 0.f;
      int yc0 = min(max(y0, 0), 13), yc1 = min(max(y1, 0), 13);
      int xc0 = min(max(x0, 0), 13), xc1 = min(max(x1, 0), 13);
      int i00 = yc0 * 14 + xc0, i01 = yc0 * 14 + xc1;
      int i10 = yc1 * 14 + xc0, i11 = yc1 * 14 + xc1;
      const float* s00 = imgT + i00 * 32; int r00 = (4 * i00) & 31;
      const float* s01 = imgT + i01 * 32; int r01 = (4 * i01) & 31;
      const float* s10 = imgT + i10 * 32; int r10 = (4 * i10) & 31;
      const float* s11 = imgT + i11 * 32; int r11 = (4 * i11) & 31;
#pragma unroll
      for (int cg = 0; cg < 8; ++cg) {
        float4 a0 = *(const float4*)(s00 + ((cg * 4 + r00) & 31));
        float4 a1 = *(const float4*)(s01 + ((cg * 4 + r01) & 31));
        float4 a2 = *(const float4*)(s10 + ((cg * 4 + r10) & 31));
        float4 a3 = *(const float4*)(s11 + ((cg * 4 + r11) & 31));
        Sbuf[(cg * 4 + 0) * SPS + pp] = fmaf(W00, a0.x, fmaf(W01, a1.x, fmaf(W10, a2.x, W11 * a3.x)));
        Sbuf[(cg * 4 + 1) * SPS + pp] = fmaf(W00, a0.y, fmaf(W01, a1.y, fmaf(W10, a2.y, W11 * a3.y)));
        Sbuf[(cg * 4 + 2) * SPS + pp] = fmaf(W00, a0.z, fmaf(W01, a1.z, fmaf(W10, a2.z, W11 * a3.z)));
        Sbuf[(cg * 4 + 3) * SPS + pp] = fmaf(W00, a0.w, fmaf(W01, a1.w, fmaf(W10, a2.w, W11 * a3.w)));
      }
    }
    __syncthreads();  // Sbuf ready; ALL offT reads for tap kk complete

    // publish NEXT tap's offsets (owners only); readers are beyond the next barrier
    if (kk < 8 && oact && (oc >> 1) == (kk + 1)) {
      float* dst = offT + (oc & 1) * 208 + op0;
#pragma unroll
      for (int i = 0; i < 16; ++i) dst[i] = oacc[i] + myob;
    }
    if (gact) {
      // (b) 32 ci in chunks of 4, prefetching chunk cb+4's weights under chunk cb's FMAs
      for (int cb = 0; cb < 32; cb += 4) {
        float4 wn[4];
        if (cb + 4 < 32) {
#pragma unroll
          for (int u = 0; u < 4; ++u)
            wn[u] = *(const float4*)(wb + (cb + 4 + u) * 576);
        }
#pragma unroll
        for (int u = 0; u < 4; ++u) {
          const float* srow = Sbuf + (cb + u) * SPS + p0;
          float4 s0 = *(const float4*)(srow);
          float4 s1 = *(const float4*)(srow + 4);
          float4 s2 = *(const float4*)(srow + 8);
          float4 s3 = *(const float4*)(srow + 12);
          float sv[16] = {s0.x, s0.y, s0.z, s0.w, s1.x, s1.y, s1.z, s1.w,
                          s2.x, s2.y, s2.z, s2.w, s3.x, s3.y, s3.z, s3.w};
          float wj[4] = {w[u].x, w[u].y, w[u].z, w[u].w};
#pragma unroll
          for (int jj = 0; jj < 4; ++jj)
#pragma unroll
            for (int i = 0; i < 16; ++i)
              acc[jj][i] = fmaf(wj[jj], sv[i], acc[jj][i]);
        }
        if (cb + 4 < 32) {
#pragma unroll
          for (int u = 0; u < 4; ++u) w[u] = wn[u];
        }
      }
    }
    __syncthreads();  // GEMM done with Sbuf; offT(kk+1) published
  }

  // ---- phase 4: ReLU + direct float4 global stores ----
  if (gact) {
    float* __restrict__ orow = h2 + b * 12544 + co0 * 196 + p0;
#pragma unroll
    for (int jj = 0; jj < 4; ++jj) {
#pragma unroll
      for (int t = 0; t < 4; ++t) {
        if (p0 + 4 * t < 196) {
          float4 v;
          v.x = fmaxf(acc[jj][4 * t + 0], 0.f);
          v.y = fmaxf(acc[jj][4 * t + 1], 0.f);
          v.z = fmaxf(acc[jj][4 * t + 2], 0.f);
          v.w = fmaxf(acc[jj][4 * t + 3], 0.f);
          *(float4*)(orow + jj * 196 + 4 * t) = v;
        }
      }
    }
  }
}

// ---------------- fc1 v1.3: K-split GEMM, 3 blocks/CU, reg-prefetched staging ----------------
__global__ __launch_bounds__(256, 3) void fc1(const float* __restrict__ h2,
                                              const float* __restrict__ fw1,
                                              float* __restrict__ part) {
  __shared__ float a_s[56 * 72];   // [k][r]
  __shared__ float b_s[56 * 132];  // [k][c]
  int tid = threadIdx.x;
  int rb = (blockIdx.x & 15) * 64;
  int ks = blockIdx.x >> 4;
  int kbase = ks * 392;
  int c0 = (tid & 31) * 4;
  int r0 = (tid >> 5) * 8;

  float4 aReg[4];
  float4 bReg[7];

  auto loadChunk = [&](int ch) {
    int kb = kbase + ch * 56;
#pragma unroll
    for (int t = 0; t < 4; ++t) {
      int idx = t * 256 + tid;
      if (idx < 896) {
        int k4 = idx % 14, r = idx / 14;
        aReg[t] = *(const float4*)&h2[(rb + r) * 12544 + kb + k4 * 4];
      }
    }
#pragma unroll
    for (int t = 0; t < 7; ++t) {
      int idx = t * 256 + tid;
      int k4 = idx % 14, c = idx / 14;
      bReg[t] = *(const float4*)&fw1[c * 12544 + kb + k4 * 4];
    }
  };

  float acc[8][4];
#pragma unroll
  for (int i = 0; i < 8; ++i)
#pragma unroll
    for (int j = 0; j < 4; ++j) acc[i][j] = 0.f;

  loadChunk(0);
  for (int ch = 0; ch < 7; ++ch) {
    __syncthreads();  // prev compute done with LDS
#pragma unroll
    for (int t = 0; t < 4; ++t) {
      int idx = t * 256 + tid;
      if (idx < 896) {
        int k4 = idx % 14, r = idx / 14;
        a_s[(k4 * 4 + 0) * 72 + r] = aReg[t].x;
        a_s[(k4 * 4 + 1) * 72 + r] = aReg[t].y;
        a_s[(k4 * 4 + 2) * 72 + r] = aReg[t].z;
        a_s[(k4 * 4 + 3) * 72 + r] = aReg[t].w;
      }
    }
#pragma unroll
    for (int t = 0; t < 7; ++t) {
      int idx = t * 256 + tid;
      int k4 = idx % 14, c = idx / 14;
      b_s[(k4 * 4 + 0) * 132 + c] = bReg[t].x;
      b_s[(k4 * 4 + 1) * 132 + c] = bReg[t].y;
      b_s[(k4 * 4 + 2) * 132 + c] = bReg[t].z;
      b_s[(k4 * 4 + 3) * 132 + c] = bReg[t].w;
    }
    __syncthreads();  // LDS ready
    if (ch < 6) loadChunk(ch + 1);  // issue next chunk's VMEM under this chunk's FMAs
    for (int k = 0; k < 56; ++k) {
      float4 bv = *(const float4*)&b_s[k * 132 + c0];
      float4 av0 = *(const float4*)&a_s[k * 72 + r0];
      float4 av1 = *(const float4*)&a_s[k * 72 + r0 + 4];
      float av[8] = {av0.x, av0.y, av0.z, av0.w, av1.x, av1.y, av1.z, av1.w};
      float bj[4] = {bv.x, bv.y, bv.z, bv.w};
#pragma unroll
      for (int i = 0; i < 8; ++i)
#pragma unroll
        for (int j = 0; j < 4; ++j) acc[i][j] = fmaf(av[i], bj[j], acc[i][j]);
    }
  }
#pragma unroll
  for (int i = 0; i < 8; ++i) {
    int r = rb + r0 + i;
#pragma unroll
    for (int j = 0; j < 4; ++j)
      part[(ks * 1024 + r) * 128 + c0 + j] = acc[i][j];
  }
}

// ---------------- reduce partials + bias + relu + fc2 (4-way ILP on the reduce) ----------------
__global__ __launch_bounds__(128) void fcfinal(const float* __restrict__ part,
                                               const float* __restrict__ fb1,
                                               const float* __restrict__ fw2,
                                               const float* __restrict__ fb2,
                                               float* __restrict__ out) {
  __shared__ float tbuf[128];
  int b = blockIdx.x, c = threadIdx.x;
  float s0 = 0.f, s1 = 0.f, s2 = 0.f, s3 = 0.f;
#pragma unroll
  for (int ks = 0; ks < 32; ks += 4) {
    s0 += part[((ks + 0) * 1024 + b) * 128 + c];
    s1 += part[((ks + 1) * 1024 + b) * 128 + c];
    s2 += part[((ks + 2) * 1024 + b) * 128 + c];
    s3 += part[((ks + 3) * 1024 + b) * 128 + c];
  }
  float s = fb1[c] + ((s0 + s1) + (s2 + s3));
  tbuf[c] = fmaxf(s, 0.f);
  __syncthreads();
  if (c < 10) {
    float v = fb2[c];
#pragma unroll
    for (int k = 0; k < 128; ++k) v = fmaf(tbuf[k], fw2[c * 128 + k], v);
    out[b * 10 + c] = v;
  }
}

extern "C" void kernel_launch(void* const* d_in, const int* in_sizes, int n_in,
                              void* d_out, int out_size, void* d_ws, size_t ws_size,
                              hipStream_t stream) {
  const float* x   = (const float*)d_in[0];
  const float* ow1 = (const float*)d_in[1];
  const float* ob1 = (const float*)d_in[2];
  const float* w1  = (const float*)d_in[3];
  const float* b1  = (const float*)d_in[4];
  const float* ow2 = (const float*)d_in[5];
  const float* ob2 = (const float*)d_in[6];
  const float* w2  = (const float*)d_in[7];
  const float* b2  = (const float*)d_in[8];
  const float* fw1 = (const float*)d_in[9];
  const float* fb1 = (const float*)d_in[10];
  const float* fw2 = (const float*)d_in[11];
  const float* fb2 = (const float*)d_in[12];
  float* ws  = (float*)d_ws;
  float* out = (float*)d_out;

  prep<<<72, 256, 0, stream>>>(w1, ow1, w2, ow2, ws);
  stage1<<<784, 256, 0, stream>>>(x, ob1, b1, ws, ws + WS_H1);
  stage2<<<NB, 256, 0, stream>>>(ws + WS_H1, ob2, b2, ws, ws + WS_H2);
  fc1<<<512, 256, 0, stream>>>(ws + WS_H2, fw1, ws + WS_PART);
  fcfinal<<<1024, 128, 0, stream>>>(ws + WS_PART, fb1, fw2, fb2, out);
}

// Round 16
// 377.228 us; speedup vs baseline: 1.0341x; 1.0182x over previous
//
#include <hip/hip_runtime.h>

// ---- sizes ----
// x: (1024,1,28,28); h1: (1024,32,14,14); h2: (1024,64,14,14)->12544; out: (1024,10)
#define NB 1024
#define TOTAL1 (NB*196)
#define SPS 200  // Sbuf pixel stride (196 real + 4 zero-pad; +8 guard at end)

// ws layout (float offsets)
#define WS_H1   0               // 1024*32*196      = 6422528
#define WS_H2   6422528         // 1024*12544      = 12845056
#define WS_PART 19267584        // 32*1024*128     = 4194304
#define WS_W1T  23461888        // 288
#define WS_OW1T 23462176        // 162
#define WS_W2T  23462338        // 18432  [k=ci*9+kk][co=64]
#define WS_OW2T 23480770        // 5184   [k=ci*9+j][c=18]

// ---------------- weight transpose prep ----------------
__global__ __launch_bounds__(256) void prep(const float* __restrict__ w1,
                                            const float* __restrict__ ow1,
                                            const float* __restrict__ w2,
                                            const float* __restrict__ ow2,
                                            float* __restrict__ ws) {
  int i = blockIdx.x * 256 + threadIdx.x;
  if (i < 288)   { int co = i / 9,  kk = i % 9;   ws[WS_W1T  + kk * 32 + co] = w1[i]; }
  if (i < 162)   { int c  = i / 9,  j  = i % 9;   ws[WS_OW1T + j  * 18 + c ] = ow1[i]; }
  if (i < 18432) { int co = i / 288, k = i % 288; ws[WS_W2T  + k  * 64 + co] = w2[i]; }
  if (i < 5184)  { int c  = i / 288, k = i % 288; ws[WS_OW2T + k  * 18 + c ] = ow2[i]; }
}

// ---------------- stage 1: offset conv + deform conv (1->32) + relu + pool 28->14 ----------------
__global__ __launch_bounds__(256, 2) void stage1(const float* __restrict__ x,
                                                 const float* __restrict__ ob1,
                                                 const float* __restrict__ b1,
                                                 const float* __restrict__ ws,
                                                 float* __restrict__ h1) {
  __shared__ float ximg[3 * 784];
  const float* __restrict__ w1t  = ws + WS_W1T;   // [kk][32]
  const float* __restrict__ ow1t = ws + WS_OW1T;  // [j][18]
  int tid = threadIdx.x;
  int g0 = blockIdx.x * 256;
  int bfirst = g0 / 196;
  for (int idx = tid; idx < 3 * 784; idx += 256) {
    int img = idx / 784;
    int b = bfirst + img;
    ximg[idx] = (b < NB) ? x[b * 784 + (idx - img * 784)] : 0.f;
  }
  __syncthreads();
  int g = g0 + tid;
  if (g >= TOTAL1) return;
  int b = g / 196, p = g - b * 196;
  const float* im = ximg + (b - bfirst) * 784;
  int oy = p / 14, ox = p - (p / 14) * 14;

  float pooled[32];
#pragma unroll
  for (int co = 0; co < 32; ++co) pooled[co] = 0.f;

  for (int sub = 0; sub < 4; ++sub) {
    int y  = 2 * oy + (sub >> 1);
    int ix = 2 * ox + (sub & 1);
    float patch[9];
#pragma unroll
    for (int j = 0; j < 9; ++j) {
      int yy = y + j / 3 - 1, xc = ix + j % 3 - 1;
      bool ok = (yy >= 0) & (yy < 28) & (xc >= 0) & (xc < 28);
      patch[j] = ok ? im[yy * 28 + xc] : 0.f;
    }
    float off[18];
#pragma unroll
    for (int c = 0; c < 18; ++c) off[c] = ob1[c];
#pragma unroll
    for (int j = 0; j < 9; ++j) {
      float v = patch[j];
#pragma unroll
      for (int c = 0; c < 18; ++c) off[c] = fmaf(v, ow1t[j * 18 + c], off[c]);
    }
    float a[32];
#pragma unroll
    for (int co = 0; co < 32; ++co) a[co] = b1[co];
#pragma unroll
    for (int kk = 0; kk < 9; ++kk) {
      float py = (float)(y - 1 + kk / 3) + off[2 * kk];
      float px = (float)(ix - 1 + kk % 3) + off[2 * kk + 1];
      float y0f = floorf(py), x0f = floorf(px);
      float wy1 = py - y0f, wx1 = px - x0f;
      float wy0 = 1.f - wy1, wx0 = 1.f - wx1;
      int y0 = (int)y0f, x0 = (int)x0f;
      int y1 = y0 + 1, x1 = x0 + 1;
      bool vy0 = (y0 >= 0) & (y0 < 28), vy1 = (y1 >= 0) & (y1 < 28);
      bool vx0 = (x0 >= 0) & (x0 < 28), vx1 = (x1 >= 0) & (x1 < 28);
      float W00 = (vy0 & vx0) ? wy0 * wx0 : 0.f;
      float W01 = (vy0 & vx1) ? wy0 * wx1 : 0.f;
      float W10 = (vy1 & vx0) ? wy1 * wx0 : 0.f;
      float W11 = (vy1 & vx1) ? wy1 * wx1 : 0.f;
      int yc0 = min(max(y0, 0), 27), yc1 = min(max(y1, 0), 27);
      int xc0 = min(max(x0, 0), 27), xc1 = min(max(x1, 0), 27);
      float s = im[yc0 * 28 + xc0] * W00 + im[yc0 * 28 + xc1] * W01 +
                im[yc1 * 28 + xc0] * W10 + im[yc1 * 28 + xc1] * W11;
#pragma unroll
      for (int co = 0; co < 32; ++co) a[co] = fmaf(s, w1t[kk * 32 + co], a[co]);
    }
#pragma unroll
    for (int co = 0; co < 32; ++co) pooled[co] += fmaxf(a[co], 0.f);
  }
#pragma unroll
  for (int co = 0; co < 32; ++co) h1[b * 6272 + co * 196 + p] = pooled[co] * 0.25f;
}

// ---------------- stage 2 v4.3 (round-13 verbatim, best measured): hoisted weights + prefetch ----------------
// LDS: imgT 25088B + Sbuf 25632B + offT 1664B = 52384B -> 3 blocks/CU (12 waves).
// Prefetch pattern (validated R12/R13): VMEM loads issue a full phase before use;
//  phase 2: wv[32] hoisted above the tap's sampler (2 barriers + LDS writes of cover);
//  phase 3: tap's first w-chunk before the sampler, chunk cb+4 under chunk cb's FMAs.
__global__ __launch_bounds__(256, 3) void stage2(const float* __restrict__ h1,
                                                 const float* __restrict__ ob2,
                                                 const float* __restrict__ b2,
                                                 const float* __restrict__ ws,
                                                 float* __restrict__ h2) {
  __shared__ float imgT[196 * 32];       // imgT[p*32 + ((ci+4p)&31)] = img[ci][p]
  __shared__ float Sbuf[32 * SPS + 8];   // S[ci*SPS + p]; +8 guard for pg=12 over-reads
  __shared__ float offT[2 * 208];        // current tap's (dy,dx); 208-stride keeps spills in-row
  const float* __restrict__ w2t  = ws + WS_W2T;
  const float* __restrict__ ow2t = ws + WS_OW2T;
  int tid = threadIdx.x;
  int b = blockIdx.x;

  // ---- phase 1: load image, transposed + bank-rotated; zero Sbuf guard ONCE ----
  for (int e = tid; e < 6272; e += 256) {
    int ci = e / 196, p = e - ci * 196;
    imgT[p * 32 + ((ci + 4 * p) & 31)] = h1[b * 6272 + e];
  }
  if (tid < 128) Sbuf[(tid >> 2) * SPS + 196 + (tid & 3)] = 0.f;  // rows 0..31, cols 196..199
  if (tid < 8)   Sbuf[32 * SPS + tid] = 0.f;                      // tail guard

  // sampler identity
  int pp = tid;
  int spy = pp / 14, spx = pp - (pp / 14) * 14;

  // offset-GEMM identity: 18 channels x 13 pixel-groups of 16 = 234 threads
  int oc  = tid % 18;
  int opg = tid / 18;
  int op0 = opg * 16;
  bool oact = (tid < 234);
  float oacc[16];
#pragma unroll
  for (int i = 0; i < 16; ++i) oacc[i] = 0.f;

  // ---- phase 2: offset conv as 9 broadcast-GEMM taps (integer shifts) ----
  for (int j = 0; j < 9; ++j) {
    // hoisted weight loads for this tap (consumed after 2 barriers + sampler)
    float wv[32];
    if (oact) {
#pragma unroll
      for (int ci2 = 0; ci2 < 32; ++ci2) wv[ci2] = ow2t[(ci2 * 9 + j) * 18 + oc];
    }
    __syncthreads();
    if (pp < 196) {
      int yy = spy + j / 3 - 1, xx = spx + j % 3 - 1;
      bool ok = (yy >= 0) & (yy < 14) & (xx >= 0) & (xx < 14);
      int idx = ok ? (yy * 14 + xx) : 0;
      const float* src = imgT + idx * 32;
      int rot = (4 * idx) & 31;
#pragma unroll
      for (int cg = 0; cg < 8; ++cg) {
        float4 v;
        if (ok) v = *(const float4*)(src + ((cg * 4 + rot) & 31));
        else    v = make_float4(0.f, 0.f, 0.f, 0.f);
        Sbuf[(cg * 4 + 0) * SPS + pp] = v.x;
        Sbuf[(cg * 4 + 1) * SPS + pp] = v.y;
        Sbuf[(cg * 4 + 2) * SPS + pp] = v.z;
        Sbuf[(cg * 4 + 3) * SPS + pp] = v.w;
      }
    }
    __syncthreads();
    if (oact) {
      for (int ci2 = 0; ci2 < 32; ++ci2) {
        const float* srow = Sbuf + ci2 * SPS + op0;
        float w = wv[ci2];
#pragma unroll
        for (int t = 0; t < 4; ++t) {
          float4 s = *(const float4*)(srow + 4 * t);
          oacc[4 * t + 0] = fmaf(w, s.x, oacc[4 * t + 0]);
          oacc[4 * t + 1] = fmaf(w, s.y, oacc[4 * t + 1]);
          oacc[4 * t + 2] = fmaf(w, s.z, oacc[4 * t + 2]);
          oacc[4 * t + 3] = fmaf(w, s.w, oacc[4 * t + 3]);
        }
      }
    }
  }

  // ---- phase 3: 9 taps of publish-offsets -> sample -> weight-prefetched broadcast GEMM ----
  int cog = tid & 15, pg = tid >> 4;
  int co0 = cog * 4;
  int p0 = pg * 16;
  bool gact = (pg < 13);
  float acc[4][16];
  {
    float4 bb = *(const float4*)(b2 + co0);
    float bj[4] = {bb.x, bb.y, bb.z, bb.w};
#pragma unroll
    for (int jj = 0; jj < 4; ++jj)
#pragma unroll
      for (int i = 0; i < 16; ++i) acc[jj][i] = bj[jj];
  }
  float myob = oact ? ob2[oc] : 0.f;

  for (int kk = 0; kk < 9; ++kk) {
    __syncthreads();  // prev GEMM done with Sbuf; prev sampler done with offT
    if (oact && (oc >> 1) == kk) {
      float* dst = offT + (oc & 1) * 208 + op0;
#pragma unroll
      for (int i = 0; i < 16; ++i) dst[i] = oacc[i] + myob;
    }
    __syncthreads();  // offT ready

    // (a) issue this tap's first weight chunk NOW - hidden under the sampler section
    const float* wb = w2t + kk * 64 + co0;
    float4 w[4];
    if (gact) {
#pragma unroll
      for (int u = 0; u < 4; ++u)
        w[u] = *(const float4*)(wb + u * 576);
    }

    if (pp < 196) {
      float dyv = offT[pp];
      float dxv = offT[208 + pp];
      float pyv = (float)(spy - 1 + kk / 3) + dyv;
      float pxv = (float)(spx - 1 + kk % 3) + dxv;
      float y0f = floorf(pyv), x0f = floorf(pxv);
      float wy1 = pyv - y0f, wx1 = pxv - x0f;
      float wy0 = 1.f - wy1, wx0 = 1.f - wx1;
      int y0 = (int)y0f, x0 = (int)x0f;
      int y1 = y0 + 1, x1 = x0 + 1;
      bool vy0 = (y0 >= 0) & (y0 < 14), vy1 = (y1 >= 0) & (y1 < 14);
      bool vx0 = (x0 >= 0) & (x0 < 14), vx1 = (x1 >= 0) & (x1 < 14);
      float W00 = (vy0 & vx0) ? wy0 * wx0 : 0.f;
      float W01 = (vy0 & vx1) ? wy0 * wx1 : 0.f;
      float W10 = (vy1 & vx0) ? wy1 * wx0 : 0.f;
      float W11 = (vy1 & vx1) ? wy1 * wx1 : 0.f;
      int yc0 = min(max(y0, 0), 13), yc1 = min(max(y1, 0), 13);
      int xc0 = min(max(x0, 0), 13), xc1 = min(max(x1, 0), 13);
      int i00 = yc0 * 14 + xc0, i01 = yc0 * 14 + xc1;
      int i10 = yc1 * 14 + xc0, i11 = yc1 * 14 + xc1;
      const float* s00 = imgT + i00 * 32; int r00 = (4 * i00) & 31;
      const float* s01 = imgT + i01 * 32; int r01 = (4 * i01) & 31;
      const float* s10 = imgT + i10 * 32; int r10 = (4 * i10) & 31;
      const float* s11 = imgT + i11 * 32; int r11 = (4 * i11) & 31;
#pragma unroll
      for (int cg = 0; cg < 8; ++cg) {
        float4 a0 = *(const float4*)(s00 + ((cg * 4 + r00) & 31));
        float4 a1 = *(const float4*)(s01 + ((cg * 4 + r01) & 31));
        float4 a2 = *(const float4*)(s10 + ((cg * 4 + r10) & 31));
        float4 a3 = *(const float4*)(s11 + ((cg * 4 + r11) & 31));
        Sbuf[(cg * 4 + 0) * SPS + pp] = fmaf(W00, a0.x, fmaf(W01, a1.x, fmaf(W10, a2.x, W11 * a3.x)));
        Sbuf[(cg * 4 + 1) * SPS + pp] = fmaf(W00, a0.y, fmaf(W01, a1.y, fmaf(W10, a2.y, W11 * a3.y)));
        Sbuf[(cg * 4 + 2) * SPS + pp] = fmaf(W00, a0.z, fmaf(W01, a1.z, fmaf(W10, a2.z, W11 * a3.z)));
        Sbuf[(cg * 4 + 3) * SPS + pp] = fmaf(W00, a0.w, fmaf(W01, a1.w, fmaf(W10, a2.w, W11 * a3.w)));
      }
    }
    __syncthreads();
    if (gact) {
      // (b) 32 ci in chunks of 4, prefetching chunk cb+4's weights under chunk cb's FMAs
      for (int cb = 0; cb < 32; cb += 4) {
        float4 wn[4];
        if (cb + 4 < 32) {
#pragma unroll
          for (int u = 0; u < 4; ++u)
            wn[u] = *(const float4*)(wb + (cb + 4 + u) * 576);
        }
#pragma unroll
        for (int u = 0; u < 4; ++u) {
          const float* srow = Sbuf + (cb + u) * SPS + p0;
          float4 s0 = *(const float4*)(srow);
          float4 s1 = *(const float4*)(srow + 4);
          float4 s2 = *(const float4*)(srow + 8);
          float4 s3 = *(const float4*)(srow + 12);
          float sv[16] = {s0.x, s0.y, s0.z, s0.w, s1.x, s1.y, s1.z, s1.w,
                          s2.x, s2.y, s2.z, s2.w, s3.x, s3.y, s3.z, s3.w};
          float wj[4] = {w[u].x, w[u].y, w[u].z, w[u].w};
#pragma unroll
          for (int jj = 0; jj < 4; ++jj)
#pragma unroll
            for (int i = 0; i < 16; ++i)
              acc[jj][i] = fmaf(wj[jj], sv[i], acc[jj][i]);
        }
        if (cb + 4 < 32) {
#pragma unroll
          for (int u = 0; u < 4; ++u) w[u] = wn[u];
        }
      }
    }
  }

  // ---- phase 4: ReLU + direct float4 global stores ----
  if (gact) {
    float* __restrict__ orow = h2 + b * 12544 + co0 * 196 + p0;
#pragma unroll
    for (int jj = 0; jj < 4; ++jj) {
#pragma unroll
      for (int t = 0; t < 4; ++t) {
        if (p0 + 4 * t < 196) {
          float4 v;
          v.x = fmaxf(acc[jj][4 * t + 0], 0.f);
          v.y = fmaxf(acc[jj][4 * t + 1], 0.f);
          v.z = fmaxf(acc[jj][4 * t + 2], 0.f);
          v.w = fmaxf(acc[jj][4 * t + 3], 0.f);
          *(float4*)(orow + jj * 196 + 4 * t) = v;
        }
      }
    }
  }
}

// ---------------- fc1 v1.3: K-split GEMM, 3 blocks/CU, reg-prefetched staging ----------------
// Chunk ch+1's global loads issue at the top of chunk ch's compute (1792 FMA cover).
__global__ __launch_bounds__(256, 3) void fc1(const float* __restrict__ h2,
                                              const float* __restrict__ fw1,
                                              float* __restrict__ part) {
  __shared__ float a_s[56 * 72];   // [k][r]
  __shared__ float b_s[56 * 132];  // [k][c]
  int tid = threadIdx.x;
  int rb = (blockIdx.x & 15) * 64;
  int ks = blockIdx.x >> 4;
  int kbase = ks * 392;
  int c0 = (tid & 31) * 4;
  int r0 = (tid >> 5) * 8;

  float4 aReg[4];
  float4 bReg[7];

  auto loadChunk = [&](int ch) {
    int kb = kbase + ch * 56;
#pragma unroll
    for (int t = 0; t < 4; ++t) {
      int idx = t * 256 + tid;
      if (idx < 896) {
        int k4 = idx % 14, r = idx / 14;
        aReg[t] = *(const float4*)&h2[(rb + r) * 12544 + kb + k4 * 4];
      }
    }
#pragma unroll
    for (int t = 0; t < 7; ++t) {
      int idx = t * 256 + tid;
      int k4 = idx % 14, c = idx / 14;
      bReg[t] = *(const float4*)&fw1[c * 12544 + kb + k4 * 4];
    }
  };

  float acc[8][4];
#pragma unroll
  for (int i = 0; i < 8; ++i)
#pragma unroll
    for (int j = 0; j < 4; ++j) acc[i][j] = 0.f;

  loadChunk(0);
  for (int ch = 0; ch < 7; ++ch) {
    __syncthreads();  // prev compute done with LDS
#pragma unroll
    for (int t = 0; t < 4; ++t) {
      int idx = t * 256 + tid;
      if (idx < 896) {
        int k4 = idx % 14, r = idx / 14;
        a_s[(k4 * 4 + 0) * 72 + r] = aReg[t].x;
        a_s[(k4 * 4 + 1) * 72 + r] = aReg[t].y;
        a_s[(k4 * 4 + 2) * 72 + r] = aReg[t].z;
        a_s[(k4 * 4 + 3) * 72 + r] = aReg[t].w;
      }
    }
#pragma unroll
    for (int t = 0; t < 7; ++t) {
      int idx = t * 256 + tid;
      int k4 = idx % 14, c = idx / 14;
      b_s[(k4 * 4 + 0) * 132 + c] = bReg[t].x;
      b_s[(k4 * 4 + 1) * 132 + c] = bReg[t].y;
      b_s[(k4 * 4 + 2) * 132 + c] = bReg[t].z;
      b_s[(k4 * 4 + 3) * 132 + c] = bReg[t].w;
    }
    __syncthreads();  // LDS ready
    if (ch < 6) loadChunk(ch + 1);  // issue next chunk's VMEM under this chunk's FMAs
    for (int k = 0; k < 56; ++k) {
      float4 bv = *(const float4*)&b_s[k * 132 + c0];
      float4 av0 = *(const float4*)&a_s[k * 72 + r0];
      float4 av1 = *(const float4*)&a_s[k * 72 + r0 + 4];
      float av[8] = {av0.x, av0.y, av0.z, av0.w, av1.x, av1.y, av1.z, av1.w};
      float bj[4] = {bv.x, bv.y, bv.z, bv.w};
#pragma unroll
      for (int i = 0; i < 8; ++i)
#pragma unroll
        for (int j = 0; j < 4; ++j) acc[i][j] = fmaf(av[i], bj[j], acc[i][j]);
    }
  }
#pragma unroll
  for (int i = 0; i < 8; ++i) {
    int r = rb + r0 + i;
#pragma unroll
    for (int j = 0; j < 4; ++j)
      part[(ks * 1024 + r) * 128 + c0 + j] = acc[i][j];
  }
}

// ---------------- reduce partials + bias + relu + fc2 (4-way ILP on the reduce) ----------------
__global__ __launch_bounds__(128) void fcfinal(const float* __restrict__ part,
                                               const float* __restrict__ fb1,
                                               const float* __restrict__ fw2,
                                               const float* __restrict__ fb2,
                                               float* __restrict__ out) {
  __shared__ float tbuf[128];
  int b = blockIdx.x, c = threadIdx.x;
  float s0 = 0.f, s1 = 0.f, s2 = 0.f, s3 = 0.f;
#pragma unroll
  for (int ks = 0; ks < 32; ks += 4) {
    s0 += part[((ks + 0) * 1024 + b) * 128 + c];
    s1 += part[((ks + 1) * 1024 + b) * 128 + c];
    s2 += part[((ks + 2) * 1024 + b) * 128 + c];
    s3 += part[((ks + 3) * 1024 + b) * 128 + c];
  }
  float s = fb1[c] + ((s0 + s1) + (s2 + s3));
  tbuf[c] = fmaxf(s, 0.f);
  __syncthreads();
  if (c < 10) {
    float v = fb2[c];
#pragma unroll
    for (int k = 0; k < 128; ++k) v = fmaf(tbuf[k], fw2[c * 128 + k], v);
    out[b * 10 + c] = v;
  }
}

extern "C" void kernel_launch(void* const* d_in, const int* in_sizes, int n_in,
                              void* d_out, int out_size, void* d_ws, size_t ws_size,
                              hipStream_t stream) {
  const float* x   = (const float*)d_in[0];
  const float* ow1 = (const float*)d_in[1];
  const float* ob1 = (const float*)d_in[2];
  const float* w1  = (const float*)d_in[3];
  const float* b1  = (const float*)d_in[4];
  const float* ow2 = (const float*)d_in[5];
  const float* ob2 = (const float*)d_in[6];
  const float* w2  = (const float*)d_in[7];
  const float* b2  = (const float*)d_in[8];
  const float* fw1 = (const float*)d_in[9];
  const float* fb1 = (const float*)d_in[10];
  const float* fw2 = (const float*)d_in[11];
  const float* fb2 = (const float*)d_in[12];
  float* ws  = (float*)d_ws;
  float* out = (float*)d_out;

  prep<<<72, 256, 0, stream>>>(w1, ow1, w2, ow2, ws);
  stage1<<<784, 256, 0, stream>>>(x, ob1, b1, ws, ws + WS_H1);
  stage2<<<NB, 256, 0, stream>>>(ws + WS_H1, ob2, b2, ws, ws + WS_H2);
  fc1<<<512, 256, 0, stream>>>(ws + WS_H2, fw1, ws + WS_PART);
  fcfinal<<<1024, 128, 0, stream>>>(ws + WS_PART, fb1, fw2, fb2, out);
}

// Round 17
// 373.412 us; speedup vs baseline: 1.0447x; 1.0102x over previous
//
#include <hip/hip_runtime.h>

// ---- sizes ----
// x: (1024,1,28,28); h1: (1024,32,14,14); h2: (1024,64,14,14)->12544; out: (1024,10)
#define NB 1024
#define TOTAL1 (NB*196)
#define SPS 200  // Sbuf pixel stride (196 real + 4 zero-pad; +8 guard at end)

// ws layout (float offsets)
#define WS_H1   0               // 1024*32*196      = 6422528
#define WS_H2   6422528         // 1024*12544      = 12845056
#define WS_PART 19267584        // 32*1024*128     = 4194304
#define WS_W1T  23461888        // 288
#define WS_OW1T 23462176        // 162
#define WS_W2T  23462338        // 18432  [k=ci*9+kk][co=64]
#define WS_OW2T 23480770        // 5184   [k=ci*9+j][c=18]

// ---------------- weight transpose prep ----------------
__global__ __launch_bounds__(256) void prep(const float* __restrict__ w1,
                                            const float* __restrict__ ow1,
                                            const float* __restrict__ w2,
                                            const float* __restrict__ ow2,
                                            float* __restrict__ ws) {
  int i = blockIdx.x * 256 + threadIdx.x;
  if (i < 288)   { int co = i / 9,  kk = i % 9;   ws[WS_W1T  + kk * 32 + co] = w1[i]; }
  if (i < 162)   { int c  = i / 9,  j  = i % 9;   ws[WS_OW1T + j  * 18 + c ] = ow1[i]; }
  if (i < 18432) { int co = i / 288, k = i % 288; ws[WS_W2T  + k  * 64 + co] = w2[i]; }
  if (i < 5184)  { int c  = i / 288, k = i % 288; ws[WS_OW2T + k  * 18 + c ] = ow2[i]; }
}

// ---------------- stage 1: offset conv + deform conv (1->32) + relu + pool 28->14 ----------------
__global__ __launch_bounds__(256, 2) void stage1(const float* __restrict__ x,
                                                 const float* __restrict__ ob1,
                                                 const float* __restrict__ b1,
                                                 const float* __restrict__ ws,
                                                 float* __restrict__ h1) {
  __shared__ float ximg[3 * 784];
  const float* __restrict__ w1t  = ws + WS_W1T;   // [kk][32]
  const float* __restrict__ ow1t = ws + WS_OW1T;  // [j][18]
  int tid = threadIdx.x;
  int g0 = blockIdx.x * 256;
  int bfirst = g0 / 196;
  for (int idx = tid; idx < 3 * 784; idx += 256) {
    int img = idx / 784;
    int b = bfirst + img;
    ximg[idx] = (b < NB) ? x[b * 784 + (idx - img * 784)] : 0.f;
  }
  __syncthreads();
  int g = g0 + tid;
  if (g >= TOTAL1) return;
  int b = g / 196, p = g - b * 196;
  const float* im = ximg + (b - bfirst) * 784;
  int oy = p / 14, ox = p - (p / 14) * 14;

  float pooled[32];
#pragma unroll
  for (int co = 0; co < 32; ++co) pooled[co] = 0.f;

  for (int sub = 0; sub < 4; ++sub) {
    int y  = 2 * oy + (sub >> 1);
    int ix = 2 * ox + (sub & 1);
    float patch[9];
#pragma unroll
    for (int j = 0; j < 9; ++j) {
      int yy = y + j / 3 - 1, xc = ix + j % 3 - 1;
      bool ok = (yy >= 0) & (yy < 28) & (xc >= 0) & (xc < 28);
      patch[j] = ok ? im[yy * 28 + xc] : 0.f;
    }
    float off[18];
#pragma unroll
    for (int c = 0; c < 18; ++c) off[c] = ob1[c];
#pragma unroll
    for (int j = 0; j < 9; ++j) {
      float v = patch[j];
#pragma unroll
      for (int c = 0; c < 18; ++c) off[c] = fmaf(v, ow1t[j * 18 + c], off[c]);
    }
    float a[32];
#pragma unroll
    for (int co = 0; co < 32; ++co) a[co] = b1[co];
#pragma unroll
    for (int kk = 0; kk < 9; ++kk) {
      float py = (float)(y - 1 + kk / 3) + off[2 * kk];
      float px = (float)(ix - 1 + kk % 3) + off[2 * kk + 1];
      float y0f = floorf(py), x0f = floorf(px);
      float wy1 = py - y0f, wx1 = px - x0f;
      float wy0 = 1.f - wy1, wx0 = 1.f - wx1;
      int y0 = (int)y0f, x0 = (int)x0f;
      int y1 = y0 + 1, x1 = x0 + 1;
      bool vy0 = (y0 >= 0) & (y0 < 28), vy1 = (y1 >= 0) & (y1 < 28);
      bool vx0 = (x0 >= 0) & (x0 < 28), vx1 = (x1 >= 0) & (x1 < 28);
      float W00 = (vy0 & vx0) ? wy0 * wx0 : 0.f;
      float W01 = (vy0 & vx1) ? wy0 * wx1 : 0.f;
      float W10 = (vy1 & vx0) ? wy1 * wx0 : 0.f;
      float W11 = (vy1 & vx1) ? wy1 * wx1 : 0.f;
      int yc0 = min(max(y0, 0), 27), yc1 = min(max(y1, 0), 27);
      int xc0 = min(max(x0, 0), 27), xc1 = min(max(x1, 0), 27);
      float s = im[yc0 * 28 + xc0] * W00 + im[yc0 * 28 + xc1] * W01 +
                im[yc1 * 28 + xc0] * W10 + im[yc1 * 28 + xc1] * W11;
#pragma unroll
      for (int co = 0; co < 32; ++co) a[co] = fmaf(s, w1t[kk * 32 + co], a[co]);
    }
#pragma unroll
    for (int co = 0; co < 32; ++co) pooled[co] += fmaxf(a[co], 0.f);
  }
#pragma unroll
  for (int co = 0; co < 32; ++co) h1[b * 6272 + co * 196 + p] = pooled[co] * 0.25f;
}

// ---------------- stage 2 v4.3 (round-13 verbatim, best measured): hoisted weights + prefetch ----------------
__global__ __launch_bounds__(256, 3) void stage2(const float* __restrict__ h1,
                                                 const float* __restrict__ ob2,
                                                 const float* __restrict__ b2,
                                                 const float* __restrict__ ws,
                                                 float* __restrict__ h2) {
  __shared__ float imgT[196 * 32];       // imgT[p*32 + ((ci+4p)&31)] = img[ci][p]
  __shared__ float Sbuf[32 * SPS + 8];   // S[ci*SPS + p]; +8 guard for pg=12 over-reads
  __shared__ float offT[2 * 208];        // current tap's (dy,dx); 208-stride keeps spills in-row
  const float* __restrict__ w2t  = ws + WS_W2T;
  const float* __restrict__ ow2t = ws + WS_OW2T;
  int tid = threadIdx.x;
  int b = blockIdx.x;

  // ---- phase 1: load image, transposed + bank-rotated; zero Sbuf guard ONCE ----
  for (int e = tid; e < 6272; e += 256) {
    int ci = e / 196, p = e - ci * 196;
    imgT[p * 32 + ((ci + 4 * p) & 31)] = h1[b * 6272 + e];
  }
  if (tid < 128) Sbuf[(tid >> 2) * SPS + 196 + (tid & 3)] = 0.f;  // rows 0..31, cols 196..199
  if (tid < 8)   Sbuf[32 * SPS + tid] = 0.f;                      // tail guard

  // sampler identity
  int pp = tid;
  int spy = pp / 14, spx = pp - (pp / 14) * 14;

  // offset-GEMM identity: 18 channels x 13 pixel-groups of 16 = 234 threads
  int oc  = tid % 18;
  int opg = tid / 18;
  int op0 = opg * 16;
  bool oact = (tid < 234);
  float oacc[16];
#pragma unroll
  for (int i = 0; i < 16; ++i) oacc[i] = 0.f;

  // ---- phase 2: offset conv as 9 broadcast-GEMM taps (integer shifts) ----
  for (int j = 0; j < 9; ++j) {
    // hoisted weight loads for this tap (consumed after 2 barriers + sampler)
    float wv[32];
    if (oact) {
#pragma unroll
      for (int ci2 = 0; ci2 < 32; ++ci2) wv[ci2] = ow2t[(ci2 * 9 + j) * 18 + oc];
    }
    __syncthreads();
    if (pp < 196) {
      int yy = spy + j / 3 - 1, xx = spx + j % 3 - 1;
      bool ok = (yy >= 0) & (yy < 14) & (xx >= 0) & (xx < 14);
      int idx = ok ? (yy * 14 + xx) : 0;
      const float* src = imgT + idx * 32;
      int rot = (4 * idx) & 31;
#pragma unroll
      for (int cg = 0; cg < 8; ++cg) {
        float4 v;
        if (ok) v = *(const float4*)(src + ((cg * 4 + rot) & 31));
        else    v = make_float4(0.f, 0.f, 0.f, 0.f);
        Sbuf[(cg * 4 + 0) * SPS + pp] = v.x;
        Sbuf[(cg * 4 + 1) * SPS + pp] = v.y;
        Sbuf[(cg * 4 + 2) * SPS + pp] = v.z;
        Sbuf[(cg * 4 + 3) * SPS + pp] = v.w;
      }
    }
    __syncthreads();
    if (oact) {
      for (int ci2 = 0; ci2 < 32; ++ci2) {
        const float* srow = Sbuf + ci2 * SPS + op0;
        float w = wv[ci2];
#pragma unroll
        for (int t = 0; t < 4; ++t) {
          float4 s = *(const float4*)(srow + 4 * t);
          oacc[4 * t + 0] = fmaf(w, s.x, oacc[4 * t + 0]);
          oacc[4 * t + 1] = fmaf(w, s.y, oacc[4 * t + 1]);
          oacc[4 * t + 2] = fmaf(w, s.z, oacc[4 * t + 2]);
          oacc[4 * t + 3] = fmaf(w, s.w, oacc[4 * t + 3]);
        }
      }
    }
  }

  // ---- phase 3: 9 taps of publish-offsets -> sample -> weight-prefetched broadcast GEMM ----
  int cog = tid & 15, pg = tid >> 4;
  int co0 = cog * 4;
  int p0 = pg * 16;
  bool gact = (pg < 13);
  float acc[4][16];
  {
    float4 bb = *(const float4*)(b2 + co0);
    float bj[4] = {bb.x, bb.y, bb.z, bb.w};
#pragma unroll
    for (int jj = 0; jj < 4; ++jj)
#pragma unroll
      for (int i = 0; i < 16; ++i) acc[jj][i] = bj[jj];
  }
  float myob = oact ? ob2[oc] : 0.f;

  for (int kk = 0; kk < 9; ++kk) {
    __syncthreads();  // prev GEMM done with Sbuf; prev sampler done with offT
    if (oact && (oc >> 1) == kk) {
      float* dst = offT + (oc & 1) * 208 + op0;
#pragma unroll
      for (int i = 0; i < 16; ++i) dst[i] = oacc[i] + myob;
    }
    __syncthreads();  // offT ready

    // (a) issue this tap's first weight chunk NOW - hidden under the sampler section
    const float* wb = w2t + kk * 64 + co0;
    float4 w[4];
    if (gact) {
#pragma unroll
      for (int u = 0; u < 4; ++u)
        w[u] = *(const float4*)(wb + u * 576);
    }

    if (pp < 196) {
      float dyv = offT[pp];
      float dxv = offT[208 + pp];
      float pyv = (float)(spy - 1 + kk / 3) + dyv;
      float pxv = (float)(spx - 1 + kk % 3) + dxv;
      float y0f = floorf(pyv), x0f = floorf(pxv);
      float wy1 = pyv - y0f, wx1 = pxv - x0f;
      float wy0 = 1.f - wy1, wx0 = 1.f - wx1;
      int y0 = (int)y0f, x0 = (int)x0f;
      int y1 = y0 + 1, x1 = x0 + 1;
      bool vy0 = (y0 >= 0) & (y0 < 14), vy1 = (y1 >= 0) & (y1 < 14);
      bool vx0 = (x0 >= 0) & (x0 < 14), vx1 = (x1 >= 0) & (x1 < 14);
      float W00 = (vy0 & vx0) ? wy0 * wx0 : 0.f;
      float W01 = (vy0 & vx1) ? wy0 * wx1 : 0.f;
      float W10 = (vy1 & vx0) ? wy1 * wx0 : 0.f;
      float W11 = (vy1 & vx1) ? wy1 * wx1 : 0.f;
      int yc0 = min(max(y0, 0), 13), yc1 = min(max(y1, 0), 13);
      int xc0 = min(max(x0, 0), 13), xc1 = min(max(x1, 0), 13);
      int i00 = yc0 * 14 + xc0, i01 = yc0 * 14 + xc1;
      int i10 = yc1 * 14 + xc0, i11 = yc1 * 14 + xc1;
      const float* s00 = imgT + i00 * 32; int r00 = (4 * i00) & 31;
      const float* s01 = imgT + i01 * 32; int r01 = (4 * i01) & 31;
      const float* s10 = imgT + i10 * 32; int r10 = (4 * i10) & 31;
      const float* s11 = imgT + i11 * 32; int r11 = (4 * i11) & 31;
#pragma unroll
      for (int cg = 0; cg < 8; ++cg) {
        float4 a0 = *(const float4*)(s00 + ((cg * 4 + r00) & 31));
        float4 a1 = *(const float4*)(s01 + ((cg * 4 + r01) & 31));
        float4 a2 = *(const float4*)(s10 + ((cg * 4 + r10) & 31));
        float4 a3 = *(const float4*)(s11 + ((cg * 4 + r11) & 31));
        Sbuf[(cg * 4 + 0) * SPS + pp] = fmaf(W00, a0.x, fmaf(W01, a1.x, fmaf(W10, a2.x, W11 * a3.x)));
        Sbuf[(cg * 4 + 1) * SPS + pp] = fmaf(W00, a0.y, fmaf(W01, a1.y, fmaf(W10, a2.y, W11 * a3.y)));
        Sbuf[(cg * 4 + 2) * SPS + pp] = fmaf(W00, a0.z, fmaf(W01, a1.z, fmaf(W10, a2.z, W11 * a3.z)));
        Sbuf[(cg * 4 + 3) * SPS + pp] = fmaf(W00, a0.w, fmaf(W01, a1.w, fmaf(W10, a2.w, W11 * a3.w)));
      }
    }
    __syncthreads();
    if (gact) {
      // (b) 32 ci in chunks of 4, prefetching chunk cb+4's weights under chunk cb's FMAs
      for (int cb = 0; cb < 32; cb += 4) {
        float4 wn[4];
        if (cb + 4 < 32) {
#pragma unroll
          for (int u = 0; u < 4; ++u)
            wn[u] = *(const float4*)(wb + (cb + 4 + u) * 576);
        }
#pragma unroll
        for (int u = 0; u < 4; ++u) {
          const float* srow = Sbuf + (cb + u) * SPS + p0;
          float4 s0 = *(const float4*)(srow);
          float4 s1 = *(const float4*)(srow + 4);
          float4 s2 = *(const float4*)(srow + 8);
          float4 s3 = *(const float4*)(srow + 12);
          float sv[16] = {s0.x, s0.y, s0.z, s0.w, s1.x, s1.y, s1.z, s1.w,
                          s2.x, s2.y, s2.z, s2.w, s3.x, s3.y, s3.z, s3.w};
          float wj[4] = {w[u].x, w[u].y, w[u].z, w[u].w};
#pragma unroll
          for (int jj = 0; jj < 4; ++jj)
#pragma unroll
            for (int i = 0; i < 16; ++i)
              acc[jj][i] = fmaf(wj[jj], sv[i], acc[jj][i]);
        }
        if (cb + 4 < 32) {
#pragma unroll
          for (int u = 0; u < 4; ++u) w[u] = wn[u];
        }
      }
    }
  }

  // ---- phase 4: ReLU + direct float4 global stores ----
  if (gact) {
    float* __restrict__ orow = h2 + b * 12544 + co0 * 196 + p0;
#pragma unroll
    for (int jj = 0; jj < 4; ++jj) {
#pragma unroll
      for (int t = 0; t < 4; ++t) {
        if (p0 + 4 * t < 196) {
          float4 v;
          v.x = fmaxf(acc[jj][4 * t + 0], 0.f);
          v.y = fmaxf(acc[jj][4 * t + 1], 0.f);
          v.z = fmaxf(acc[jj][4 * t + 2], 0.f);
          v.w = fmaxf(acc[jj][4 * t + 3], 0.f);
          *(float4*)(orow + jj * 196 + 4 * t) = v;
        }
      }
    }
  }
}

// ---------------- fc1 v3: 128x128 tiles, 8x8 per thread, all 256 threads compute ----------------
// grid = 8 rb x 32 ks = 256 blocks = 1/CU, zero tail. Per k-step: 4 b128 -> 64 FMA (was 3 -> 32).
// fw1 re-read 16x -> 8x. b_s column swizzle (c + (c>>5)*4) makes the 8-stride c0 groups hit
// distinct banks (else 4-way conflict). a-side r0 in {0,8,16,24} conflict-free with 136 pad.
__global__ __launch_bounds__(256, 2) void fc1(const float* __restrict__ h2,
                                              const float* __restrict__ fw1,
                                              float* __restrict__ part) {
  __shared__ float a_s[56 * 136];  // [k][r], 128 rows + 8 pad
  __shared__ float b_s[56 * 140];  // [k][c-swizzled], 128 cols + pads at 32-col steps
  int tid = threadIdx.x;
  int rb = (blockIdx.x & 7) * 128;
  int ks = blockIdx.x >> 3;
  int kbase = ks * 392;
  int c0 = (tid & 15) * 8;
  int r0 = (tid >> 4) * 8;
  int c0s = c0 + ((c0 >> 5) << 2);  // swizzled read base (float4-safe: c0%32 <= 24)

  float4 aReg[7];
  float4 bReg[7];

  auto loadChunk = [&](int ch) {
    int kb = kbase + ch * 56;
#pragma unroll
    for (int t = 0; t < 7; ++t) {
      int idx = t * 256 + tid;  // 1792 = 128 rows x 14 k-quads
      int r = idx / 14, k4 = idx - r * 14;
      aReg[t] = *(const float4*)&h2[(rb + r) * 12544 + kb + k4 * 4];
    }
#pragma unroll
    for (int t = 0; t < 7; ++t) {
      int idx = t * 256 + tid;  // 1792 = 128 cols x 14 k-quads
      int c = idx / 14, k4 = idx - c * 14;
      bReg[t] = *(const float4*)&fw1[c * 12544 + kb + k4 * 4];
    }
  };

  float acc[8][8];
#pragma unroll
  for (int i = 0; i < 8; ++i)
#pragma unroll
    for (int j = 0; j < 8; ++j) acc[i][j] = 0.f;

  loadChunk(0);
  for (int ch = 0; ch < 7; ++ch) {
    __syncthreads();  // prev compute done with LDS
#pragma unroll
    for (int t = 0; t < 7; ++t) {
      int idx = t * 256 + tid;
      int r = idx / 14, k4 = idx - r * 14;
      a_s[(k4 * 4 + 0) * 136 + r] = aReg[t].x;
      a_s[(k4 * 4 + 1) * 136 + r] = aReg[t].y;
      a_s[(k4 * 4 + 2) * 136 + r] = aReg[t].z;
      a_s[(k4 * 4 + 3) * 136 + r] = aReg[t].w;
    }
#pragma unroll
    for (int t = 0; t < 7; ++t) {
      int idx = t * 256 + tid;
      int c = idx / 14, k4 = idx - c * 14;
      int cs = c + ((c >> 5) << 2);
      b_s[(k4 * 4 + 0) * 140 + cs] = bReg[t].x;
      b_s[(k4 * 4 + 1) * 140 + cs] = bReg[t].y;
      b_s[(k4 * 4 + 2) * 140 + cs] = bReg[t].z;
      b_s[(k4 * 4 + 3) * 140 + cs] = bReg[t].w;
    }
    __syncthreads();  // LDS ready
    if (ch < 6) loadChunk(ch + 1);  // next chunk's VMEM under this chunk's FMAs (validated R12/13)
    for (int k = 0; k < 56; ++k) {
      float4 a0 = *(const float4*)&a_s[k * 136 + r0];
      float4 a1 = *(const float4*)&a_s[k * 136 + r0 + 4];
      float4 b0 = *(const float4*)&b_s[k * 140 + c0s];
      float4 b1 = *(const float4*)&b_s[k * 140 + c0s + 4];
      float av[8] = {a0.x, a0.y, a0.z, a0.w, a1.x, a1.y, a1.z, a1.w};
      float bv[8] = {b0.x, b0.y, b0.z, b0.w, b1.x, b1.y, b1.z, b1.w};
#pragma unroll
      for (int i = 0; i < 8; ++i)
#pragma unroll
        for (int j = 0; j < 8; ++j) acc[i][j] = fmaf(av[i], bv[j], acc[i][j]);
    }
  }
#pragma unroll
  for (int i = 0; i < 8; ++i) {
    int r = rb + r0 + i;
    float* dst = part + (ks * 1024 + r) * 128 + c0;
    float4 v0 = make_float4(acc[i][0], acc[i][1], acc[i][2], acc[i][3]);
    float4 v1 = make_float4(acc[i][4], acc[i][5], acc[i][6], acc[i][7]);
    *(float4*)(dst) = v0;
    *(float4*)(dst + 4) = v1;
  }
}

// ---------------- reduce partials + bias + relu + fc2 (4-way ILP on the reduce) ----------------
__global__ __launch_bounds__(128) void fcfinal(const float* __restrict__ part,
                                               const float* __restrict__ fb1,
                                               const float* __restrict__ fw2,
                                               const float* __restrict__ fb2,
                                               float* __restrict__ out) {
  __shared__ float tbuf[128];
  int b = blockIdx.x, c = threadIdx.x;
  float s0 = 0.f, s1 = 0.f, s2 = 0.f, s3 = 0.f;
#pragma unroll
  for (int ks = 0; ks < 32; ks += 4) {
    s0 += part[((ks + 0) * 1024 + b) * 128 + c];
    s1 += part[((ks + 1) * 1024 + b) * 128 + c];
    s2 += part[((ks + 2) * 1024 + b) * 128 + c];
    s3 += part[((ks + 3) * 1024 + b) * 128 + c];
  }
  float s = fb1[c] + ((s0 + s1) + (s2 + s3));
  tbuf[c] = fmaxf(s, 0.f);
  __syncthreads();
  if (c < 10) {
    float v = fb2[c];
#pragma unroll
    for (int k = 0; k < 128; ++k) v = fmaf(tbuf[k], fw2[c * 128 + k], v);
    out[b * 10 + c] = v;
  }
}

extern "C" void kernel_launch(void* const* d_in, const int* in_sizes, int n_in,
                              void* d_out, int out_size, void* d_ws, size_t ws_size,
                              hipStream_t stream) {
  const float* x   = (const float*)d_in[0];
  const float* ow1 = (const float*)d_in[1];
  const float* ob1 = (const float*)d_in[2];
  const float* w1  = (const float*)d_in[3];
  const float* b1  = (const float*)d_in[4];
  const float* ow2 = (const float*)d_in[5];
  const float* ob2 = (const float*)d_in[6];
  const float* w2  = (const float*)d_in[7];
  const float* b2  = (const float*)d_in[8];
  const float* fw1 = (const float*)d_in[9];
  const float* fb1 = (const float*)d_in[10];
  const float* fw2 = (const float*)d_in[11];
  const float* fb2 = (const float*)d_in[12];
  float* ws  = (float*)d_ws;
  float* out = (float*)d_out;

  prep<<<72, 256, 0, stream>>>(w1, ow1, w2, ow2, ws);
  stage1<<<784, 256, 0, stream>>>(x, ob1, b1, ws, ws + WS_H1);
  stage2<<<NB, 256, 0, stream>>>(ws + WS_H1, ob2, b2, ws, ws + WS_H2);
  fc1<<<256, 256, 0, stream>>>(ws + WS_H2, fw1, ws + WS_PART);
  fcfinal<<<1024, 128, 0, stream>>>(ws + WS_PART, fb1, fw2, fb2, out);
}

// Round 18
// 367.009 us; speedup vs baseline: 1.0629x; 1.0174x over previous
//
#include <hip/hip_runtime.h>

// ---- sizes ----
// x: (1024,1,28,28); h1: (1024,32,14,14); h2: (1024,64,14,14)->12544; out: (1024,10)
#define NB 1024
#define TOTAL1 (NB*196)
#define SPS 200  // Sbuf pixel stride (196 real + 4 zero-pad; +8 guard at end)

// ws layout (float offsets)
#define WS_H1   0               // 1024*32*196      = 6422528
#define WS_H2   6422528         // 1024*12544      = 12845056
#define WS_PART 19267584        // 32*1024*128     = 4194304
#define WS_W1T  23461888        // 288
#define WS_OW1T 23462176        // 162
#define WS_W2T  23462338        // 18432  [k=ci*9+kk][co=64]
#define WS_OW2T 23480770        // 5184   [k=ci*9+j][c=18]

// ---------------- weight transpose prep ----------------
__global__ __launch_bounds__(256) void prep(const float* __restrict__ w1,
                                            const float* __restrict__ ow1,
                                            const float* __restrict__ w2,
                                            const float* __restrict__ ow2,
                                            float* __restrict__ ws) {
  int i = blockIdx.x * 256 + threadIdx.x;
  if (i < 288)   { int co = i / 9,  kk = i % 9;   ws[WS_W1T  + kk * 32 + co] = w1[i]; }
  if (i < 162)   { int c  = i / 9,  j  = i % 9;   ws[WS_OW1T + j  * 18 + c ] = ow1[i]; }
  if (i < 18432) { int co = i / 288, k = i % 288; ws[WS_W2T  + k  * 64 + co] = w2[i]; }
  if (i < 5184)  { int c  = i / 288, k = i % 288; ws[WS_OW2T + k  * 18 + c ] = ow2[i]; }
}

// ---------------- stage 1: offset conv + deform conv (1->32) + relu + pool 28->14 ----------------
__global__ __launch_bounds__(256, 2) void stage1(const float* __restrict__ x,
                                                 const float* __restrict__ ob1,
                                                 const float* __restrict__ b1,
                                                 const float* __restrict__ ws,
                                                 float* __restrict__ h1) {
  __shared__ float ximg[3 * 784];
  const float* __restrict__ w1t  = ws + WS_W1T;   // [kk][32]
  const float* __restrict__ ow1t = ws + WS_OW1T;  // [j][18]
  int tid = threadIdx.x;
  int g0 = blockIdx.x * 256;
  int bfirst = g0 / 196;
  for (int idx = tid; idx < 3 * 784; idx += 256) {
    int img = idx / 784;
    int b = bfirst + img;
    ximg[idx] = (b < NB) ? x[b * 784 + (idx - img * 784)] : 0.f;
  }
  __syncthreads();
  int g = g0 + tid;
  if (g >= TOTAL1) return;
  int b = g / 196, p = g - b * 196;
  const float* im = ximg + (b - bfirst) * 784;
  int oy = p / 14, ox = p - (p / 14) * 14;

  float pooled[32];
#pragma unroll
  for (int co = 0; co < 32; ++co) pooled[co] = 0.f;

  for (int sub = 0; sub < 4; ++sub) {
    int y  = 2 * oy + (sub >> 1);
    int ix = 2 * ox + (sub & 1);
    float patch[9];
#pragma unroll
    for (int j = 0; j < 9; ++j) {
      int yy = y + j / 3 - 1, xc = ix + j % 3 - 1;
      bool ok = (yy >= 0) & (yy < 28) & (xc >= 0) & (xc < 28);
      patch[j] = ok ? im[yy * 28 + xc] : 0.f;
    }
    float off[18];
#pragma unroll
    for (int c = 0; c < 18; ++c) off[c] = ob1[c];
#pragma unroll
    for (int j = 0; j < 9; ++j) {
      float v = patch[j];
#pragma unroll
      for (int c = 0; c < 18; ++c) off[c] = fmaf(v, ow1t[j * 18 + c], off[c]);
    }
    float a[32];
#pragma unroll
    for (int co = 0; co < 32; ++co) a[co] = b1[co];
#pragma unroll
    for (int kk = 0; kk < 9; ++kk) {
      float py = (float)(y - 1 + kk / 3) + off[2 * kk];
      float px = (float)(ix - 1 + kk % 3) + off[2 * kk + 1];
      float y0f = floorf(py), x0f = floorf(px);
      float wy1 = py - y0f, wx1 = px - x0f;
      float wy0 = 1.f - wy1, wx0 = 1.f - wx1;
      int y0 = (int)y0f, x0 = (int)x0f;
      int y1 = y0 + 1, x1 = x0 + 1;
      bool vy0 = (y0 >= 0) & (y0 < 28), vy1 = (y1 >= 0) & (y1 < 28);
      bool vx0 = (x0 >= 0) & (x0 < 28), vx1 = (x1 >= 0) & (x1 < 28);
      float W00 = (vy0 & vx0) ? wy0 * wx0 : 0.f;
      float W01 = (vy0 & vx1) ? wy0 * wx1 : 0.f;
      float W10 = (vy1 & vx0) ? wy1 * wx0 : 0.f;
      float W11 = (vy1 & vx1) ? wy1 * wx1 : 0.f;
      int yc0 = min(max(y0, 0), 27), yc1 = min(max(y1, 0), 27);
      int xc0 = min(max(x0, 0), 27), xc1 = min(max(x1, 0), 27);
      float s = im[yc0 * 28 + xc0] * W00 + im[yc0 * 28 + xc1] * W01 +
                im[yc1 * 28 + xc0] * W10 + im[yc1 * 28 + xc1] * W11;
#pragma unroll
      for (int co = 0; co < 32; ++co) a[co] = fmaf(s, w1t[kk * 32 + co], a[co]);
    }
#pragma unroll
    for (int co = 0; co < 32; ++co) pooled[co] += fmaxf(a[co], 0.f);
  }
#pragma unroll
  for (int co = 0; co < 32; ++co) h1[b * 6272 + co * 196 + p] = pooled[co] * 0.25f;
}

// ---------------- stage 2 v4.3 (best measured): hoisted weights + prefetch ----------------
// LDS: imgT 25088B + Sbuf 25632B + offT 1664B = 52384B -> 3 blocks/CU (12 waves).
// Prefetch pattern (validated R12/R13): VMEM loads issue a full phase before use;
//  phase 2: wv[32] hoisted above the tap's sampler (2 barriers + LDS writes of cover);
//  phase 3: tap's first w-chunk before the sampler, chunk cb+4 under chunk cb's FMAs.
__global__ __launch_bounds__(256, 3) void stage2(const float* __restrict__ h1,
                                                 const float* __restrict__ ob2,
                                                 const float* __restrict__ b2,
                                                 const float* __restrict__ ws,
                                                 float* __restrict__ h2) {
  __shared__ float imgT[196 * 32];       // imgT[p*32 + ((ci+4p)&31)] = img[ci][p]
  __shared__ float Sbuf[32 * SPS + 8];   // S[ci*SPS + p]; +8 guard for pg=12 over-reads
  __shared__ float offT[2 * 208];        // current tap's (dy,dx); 208-stride keeps spills in-row
  const float* __restrict__ w2t  = ws + WS_W2T;
  const float* __restrict__ ow2t = ws + WS_OW2T;
  int tid = threadIdx.x;
  int b = blockIdx.x;

  // ---- phase 1: load image, transposed + bank-rotated; zero Sbuf guard ONCE ----
  for (int e = tid; e < 6272; e += 256) {
    int ci = e / 196, p = e - ci * 196;
    imgT[p * 32 + ((ci + 4 * p) & 31)] = h1[b * 6272 + e];
  }
  if (tid < 128) Sbuf[(tid >> 2) * SPS + 196 + (tid & 3)] = 0.f;  // rows 0..31, cols 196..199
  if (tid < 8)   Sbuf[32 * SPS + tid] = 0.f;                      // tail guard

  // sampler identity
  int pp = tid;
  int spy = pp / 14, spx = pp - (pp / 14) * 14;

  // offset-GEMM identity: 18 channels x 13 pixel-groups of 16 = 234 threads
  int oc  = tid % 18;
  int opg = tid / 18;
  int op0 = opg * 16;
  bool oact = (tid < 234);
  float oacc[16];
#pragma unroll
  for (int i = 0; i < 16; ++i) oacc[i] = 0.f;

  // ---- phase 2: offset conv as 9 broadcast-GEMM taps (integer shifts) ----
  for (int j = 0; j < 9; ++j) {
    // hoisted weight loads for this tap (consumed after 2 barriers + sampler)
    float wv[32];
    if (oact) {
#pragma unroll
      for (int ci2 = 0; ci2 < 32; ++ci2) wv[ci2] = ow2t[(ci2 * 9 + j) * 18 + oc];
    }
    __syncthreads();
    if (pp < 196) {
      int yy = spy + j / 3 - 1, xx = spx + j % 3 - 1;
      bool ok = (yy >= 0) & (yy < 14) & (xx >= 0) & (xx < 14);
      int idx = ok ? (yy * 14 + xx) : 0;
      const float* src = imgT + idx * 32;
      int rot = (4 * idx) & 31;
#pragma unroll
      for (int cg = 0; cg < 8; ++cg) {
        float4 v;
        if (ok) v = *(const float4*)(src + ((cg * 4 + rot) & 31));
        else    v = make_float4(0.f, 0.f, 0.f, 0.f);
        Sbuf[(cg * 4 + 0) * SPS + pp] = v.x;
        Sbuf[(cg * 4 + 1) * SPS + pp] = v.y;
        Sbuf[(cg * 4 + 2) * SPS + pp] = v.z;
        Sbuf[(cg * 4 + 3) * SPS + pp] = v.w;
      }
    }
    __syncthreads();
    if (oact) {
      for (int ci2 = 0; ci2 < 32; ++ci2) {
        const float* srow = Sbuf + ci2 * SPS + op0;
        float w = wv[ci2];
#pragma unroll
        for (int t = 0; t < 4; ++t) {
          float4 s = *(const float4*)(srow + 4 * t);
          oacc[4 * t + 0] = fmaf(w, s.x, oacc[4 * t + 0]);
          oacc[4 * t + 1] = fmaf(w, s.y, oacc[4 * t + 1]);
          oacc[4 * t + 2] = fmaf(w, s.z, oacc[4 * t + 2]);
          oacc[4 * t + 3] = fmaf(w, s.w, oacc[4 * t + 3]);
        }
      }
    }
  }

  // ---- phase 3: 9 taps of publish-offsets -> sample -> weight-prefetched broadcast GEMM ----
  int cog = tid & 15, pg = tid >> 4;
  int co0 = cog * 4;
  int p0 = pg * 16;
  bool gact = (pg < 13);
  float acc[4][16];
  {
    float4 bb = *(const float4*)(b2 + co0);
    float bj[4] = {bb.x, bb.y, bb.z, bb.w};
#pragma unroll
    for (int jj = 0; jj < 4; ++jj)
#pragma unroll
      for (int i = 0; i < 16; ++i) acc[jj][i] = bj[jj];
  }
  float myob = oact ? ob2[oc] : 0.f;

  for (int kk = 0; kk < 9; ++kk) {
    __syncthreads();  // prev GEMM done with Sbuf; prev sampler done with offT
    if (oact && (oc >> 1) == kk) {
      float* dst = offT + (oc & 1) * 208 + op0;
#pragma unroll
      for (int i = 0; i < 16; ++i) dst[i] = oacc[i] + myob;
    }
    __syncthreads();  // offT ready

    // (a) issue this tap's first weight chunk NOW - hidden under the sampler section
    const float* wb = w2t + kk * 64 + co0;
    float4 w[4];
    if (gact) {
#pragma unroll
      for (int u = 0; u < 4; ++u)
        w[u] = *(const float4*)(wb + u * 576);
    }

    if (pp < 196) {
      float dyv = offT[pp];
      float dxv = offT[208 + pp];
      float pyv = (float)(spy - 1 + kk / 3) + dyv;
      float pxv = (float)(spx - 1 + kk % 3) + dxv;
      float y0f = floorf(pyv), x0f = floorf(pxv);
      float wy1 = pyv - y0f, wx1 = pxv - x0f;
      float wy0 = 1.f - wy1, wx0 = 1.f - wx1;
      int y0 = (int)y0f, x0 = (int)x0f;
      int y1 = y0 + 1, x1 = x0 + 1;
      bool vy0 = (y0 >= 0) & (y0 < 14), vy1 = (y1 >= 0) & (y1 < 14);
      bool vx0 = (x0 >= 0) & (x0 < 14), vx1 = (x1 >= 0) & (x1 < 14);
      float W00 = (vy0 & vx0) ? wy0 * wx0 : 0.f;
      float W01 = (vy0 & vx1) ? wy0 * wx1 : 0.f;
      float W10 = (vy1 & vx0) ? wy1 * wx0 : 0.f;
      float W11 = (vy1 & vx1) ? wy1 * wx1 : 0.f;
      int yc0 = min(max(y0, 0), 13), yc1 = min(max(y1, 0), 13);
      int xc0 = min(max(x0, 0), 13), xc1 = min(max(x1, 0), 13);
      int i00 = yc0 * 14 + xc0, i01 = yc0 * 14 + xc1;
      int i10 = yc1 * 14 + xc0, i11 = yc1 * 14 + xc1;
      const float* s00 = imgT + i00 * 32; int r00 = (4 * i00) & 31;
      const float* s01 = imgT + i01 * 32; int r01 = (4 * i01) & 31;
      const float* s10 = imgT + i10 * 32; int r10 = (4 * i10) & 31;
      const float* s11 = imgT + i11 * 32; int r11 = (4 * i11) & 31;
#pragma unroll
      for (int cg = 0; cg < 8; ++cg) {
        float4 a0 = *(const float4*)(s00 + ((cg * 4 + r00) & 31));
        float4 a1 = *(const float4*)(s01 + ((cg * 4 + r01) & 31));
        float4 a2 = *(const float4*)(s10 + ((cg * 4 + r10) & 31));
        float4 a3 = *(const float4*)(s11 + ((cg * 4 + r11) & 31));
        Sbuf[(cg * 4 + 0) * SPS + pp] = fmaf(W00, a0.x, fmaf(W01, a1.x, fmaf(W10, a2.x, W11 * a3.x)));
        Sbuf[(cg * 4 + 1) * SPS + pp] = fmaf(W00, a0.y, fmaf(W01, a1.y, fmaf(W10, a2.y, W11 * a3.y)));
        Sbuf[(cg * 4 + 2) * SPS + pp] = fmaf(W00, a0.z, fmaf(W01, a1.z, fmaf(W10, a2.z, W11 * a3.z)));
        Sbuf[(cg * 4 + 3) * SPS + pp] = fmaf(W00, a0.w, fmaf(W01, a1.w, fmaf(W10, a2.w, W11 * a3.w)));
      }
    }
    __syncthreads();
    if (gact) {
      // (b) 32 ci in chunks of 4, prefetching chunk cb+4's weights under chunk cb's FMAs
      for (int cb = 0; cb < 32; cb += 4) {
        float4 wn[4];
        if (cb + 4 < 32) {
#pragma unroll
          for (int u = 0; u < 4; ++u)
            wn[u] = *(const float4*)(wb + (cb + 4 + u) * 576);
        }
#pragma unroll
        for (int u = 0; u < 4; ++u) {
          const float* srow = Sbuf + (cb + u) * SPS + p0;
          float4 s0 = *(const float4*)(srow);
          float4 s1 = *(const float4*)(srow + 4);
          float4 s2 = *(const float4*)(srow + 8);
          float4 s3 = *(const float4*)(srow + 12);
          float sv[16] = {s0.x, s0.y, s0.z, s0.w, s1.x, s1.y, s1.z, s1.w,
                          s2.x, s2.y, s2.z, s2.w, s3.x, s3.y, s3.z, s3.w};
          float wj[4] = {w[u].x, w[u].y, w[u].z, w[u].w};
#pragma unroll
          for (int jj = 0; jj < 4; ++jj)
#pragma unroll
            for (int i = 0; i < 16; ++i)
              acc[jj][i] = fmaf(wj[jj], sv[i], acc[jj][i]);
        }
        if (cb + 4 < 32) {
#pragma unroll
          for (int u = 0; u < 4; ++u) w[u] = wn[u];
        }
      }
    }
  }

  // ---- phase 4: ReLU + direct float4 global stores ----
  if (gact) {
    float* __restrict__ orow = h2 + b * 12544 + co0 * 196 + p0;
#pragma unroll
    for (int jj = 0; jj < 4; ++jj) {
#pragma unroll
      for (int t = 0; t < 4; ++t) {
        if (p0 + 4 * t < 196) {
          float4 v;
          v.x = fmaxf(acc[jj][4 * t + 0], 0.f);
          v.y = fmaxf(acc[jj][4 * t + 1], 0.f);
          v.z = fmaxf(acc[jj][4 * t + 2], 0.f);
          v.w = fmaxf(acc[jj][4 * t + 3], 0.f);
          *(float4*)(orow + jj * 196 + 4 * t) = v;
        }
      }
    }
  }
}

// ---------------- fc1 v1.3: K-split GEMM, 3 blocks/CU, reg-prefetched staging ----------------
// Chunk ch+1's global loads issue at the top of chunk ch's compute (1792 FMA cover).
__global__ __launch_bounds__(256, 3) void fc1(const float* __restrict__ h2,
                                              const float* __restrict__ fw1,
                                              float* __restrict__ part) {
  __shared__ float a_s[56 * 72];   // [k][r]
  __shared__ float b_s[56 * 132];  // [k][c]
  int tid = threadIdx.x;
  int rb = (blockIdx.x & 15) * 64;
  int ks = blockIdx.x >> 4;
  int kbase = ks * 392;
  int c0 = (tid & 31) * 4;
  int r0 = (tid >> 5) * 8;

  float4 aReg[4];
  float4 bReg[7];

  auto loadChunk = [&](int ch) {
    int kb = kbase + ch * 56;
#pragma unroll
    for (int t = 0; t < 4; ++t) {
      int idx = t * 256 + tid;
      if (idx < 896) {
        int k4 = idx % 14, r = idx / 14;
        aReg[t] = *(const float4*)&h2[(rb + r) * 12544 + kb + k4 * 4];
      }
    }
#pragma unroll
    for (int t = 0; t < 7; ++t) {
      int idx = t * 256 + tid;
      int k4 = idx % 14, c = idx / 14;
      bReg[t] = *(const float4*)&fw1[c * 12544 + kb + k4 * 4];
    }
  };

  float acc[8][4];
#pragma unroll
  for (int i = 0; i < 8; ++i)
#pragma unroll
    for (int j = 0; j < 4; ++j) acc[i][j] = 0.f;

  loadChunk(0);
  for (int ch = 0; ch < 7; ++ch) {
    __syncthreads();  // prev compute done with LDS
#pragma unroll
    for (int t = 0; t < 4; ++t) {
      int idx = t * 256 + tid;
      if (idx < 896) {
        int k4 = idx % 14, r = idx / 14;
        a_s[(k4 * 4 + 0) * 72 + r] = aReg[t].x;
        a_s[(k4 * 4 + 1) * 72 + r] = aReg[t].y;
        a_s[(k4 * 4 + 2) * 72 + r] = aReg[t].z;
        a_s[(k4 * 4 + 3) * 72 + r] = aReg[t].w;
      }
    }
#pragma unroll
    for (int t = 0; t < 7; ++t) {
      int idx = t * 256 + tid;
      int k4 = idx % 14, c = idx / 14;
      b_s[(k4 * 4 + 0) * 132 + c] = bReg[t].x;
      b_s[(k4 * 4 + 1) * 132 + c] = bReg[t].y;
      b_s[(k4 * 4 + 2) * 132 + c] = bReg[t].z;
      b_s[(k4 * 4 + 3) * 132 + c] = bReg[t].w;
    }
    __syncthreads();  // LDS ready
    if (ch < 6) loadChunk(ch + 1);  // issue next chunk's VMEM under this chunk's FMAs
    for (int k = 0; k < 56; ++k) {
      float4 bv = *(const float4*)&b_s[k * 132 + c0];
      float4 av0 = *(const float4*)&a_s[k * 72 + r0];
      float4 av1 = *(const float4*)&a_s[k * 72 + r0 + 4];
      float av[8] = {av0.x, av0.y, av0.z, av0.w, av1.x, av1.y, av1.z, av1.w};
      float bj[4] = {bv.x, bv.y, bv.z, bv.w};
#pragma unroll
      for (int i = 0; i < 8; ++i)
#pragma unroll
        for (int j = 0; j < 4; ++j) acc[i][j] = fmaf(av[i], bj[j], acc[i][j]);
    }
  }
#pragma unroll
  for (int i = 0; i < 8; ++i) {
    int r = rb + r0 + i;
#pragma unroll
    for (int j = 0; j < 4; ++j)
      part[(ks * 1024 + r) * 128 + c0 + j] = acc[i][j];
  }
}

// ---------------- reduce partials + bias + relu + fc2 (4-way ILP on the reduce) ----------------
__global__ __launch_bounds__(128) void fcfinal(const float* __restrict__ part,
                                               const float* __restrict__ fb1,
                                               const float* __restrict__ fw2,
                                               const float* __restrict__ fb2,
                                               float* __restrict__ out) {
  __shared__ float tbuf[128];
  int b = blockIdx.x, c = threadIdx.x;
  float s0 = 0.f, s1 = 0.f, s2 = 0.f, s3 = 0.f;
#pragma unroll
  for (int ks = 0; ks < 32; ks += 4) {
    s0 += part[((ks + 0) * 1024 + b) * 128 + c];
    s1 += part[((ks + 1) * 1024 + b) * 128 + c];
    s2 += part[((ks + 2) * 1024 + b) * 128 + c];
    s3 += part[((ks + 3) * 1024 + b) * 128 + c];
  }
  float s = fb1[c] + ((s0 + s1) + (s2 + s3));
  tbuf[c] = fmaxf(s, 0.f);
  __syncthreads();
  if (c < 10) {
    float v = fb2[c];
#pragma unroll
    for (int k = 0; k < 128; ++k) v = fmaf(tbuf[k], fw2[c * 128 + k], v);
    out[b * 10 + c] = v;
  }
}

extern "C" void kernel_launch(void* const* d_in, const int* in_sizes, int n_in,
                              void* d_out, int out_size, void* d_ws, size_t ws_size,
                              hipStream_t stream) {
  const float* x   = (const float*)d_in[0];
  const float* ow1 = (const float*)d_in[1];
  const float* ob1 = (const float*)d_in[2];
  const float* w1  = (const float*)d_in[3];
  const float* b1  = (const float*)d_in[4];
  const float* ow2 = (const float*)d_in[5];
  const float* ob2 = (const float*)d_in[6];
  const float* w2  = (const float*)d_in[7];
  const float* b2  = (const float*)d_in[8];
  const float* fw1 = (const float*)d_in[9];
  const float* fb1 = (const float*)d_in[10];
  const float* fw2 = (const float*)d_in[11];
  const float* fb2 = (const float*)d_in[12];
  float* ws  = (float*)d_ws;
  float* out = (float*)d_out;

  prep<<<72, 256, 0, stream>>>(w1, ow1, w2, ow2, ws);
  stage1<<<784, 256, 0, stream>>>(x, ob1, b1, ws, ws + WS_H1);
  stage2<<<NB, 256, 0, stream>>>(ws + WS_H1, ob2, b2, ws, ws + WS_H2);
  fc1<<<512, 256, 0, stream>>>(ws + WS_H2, fw1, ws + WS_PART);
  fcfinal<<<1024, 128, 0, stream>>>(ws + WS_PART, fb1, fw2, fb2, out);
}